// Round 1
// baseline (1158.727 us; speedup 1.0000x reference)
//
#include <hip/hip_runtime.h>

#define HW_N 2304
#define EPS_F 1e-5f

constexpr int TILE = 64;
constexpr int KB = 16;

struct Six { const float* p[6]; };

// ---------------------------------------------------------------------------
// Generic 64x64 fp32 GEMM tile core: Y[m0:m0+64, n0:n0+64] = W[M,K] * X[K,N]
// X is given as two stacked buffers (concat over K): k < K1 -> x1, else x2.
// ---------------------------------------------------------------------------
__device__ __forceinline__ void gemm_tile_core(
    const float* __restrict__ x1, const float* __restrict__ x2, int K1,
    const float* __restrict__ W, int K, int N, int m0, int n0,
    float (*Ws)[KB + 4], float (*Xs)[TILE], float acc[4][4])
{
    const int tid = threadIdx.x;
    const int wr = tid >> 2;            // 0..63 W-tile row
    const int wc = (tid & 3) * 4;       // 0,4,8,12
    const int xr = tid >> 4;            // 0..15 X-tile row
    const int xc = (tid & 15) * 4;      // 0..60
    const int tx = tid & 15, ty = tid >> 4;

    for (int kb = 0; kb < K; kb += KB) {
        __syncthreads();
        // W tile: 64 rows x 16 k
        *(float4*)(&Ws[wr][wc]) =
            *(const float4*)(W + (long long)(m0 + wr) * K + kb + wc);
        // X tile: 16 k x 64 cols
        {
            const int k = kb + xr;
            const float* src = (k < K1) ? (x1 + (long long)k * N)
                                        : (x2 + (long long)(k - K1) * N);
            *(float4*)(&Xs[xr][xc]) = *(const float4*)(src + n0 + xc);
        }
        __syncthreads();
#pragma unroll
        for (int kk = 0; kk < KB; ++kk) {
            const float a0 = Ws[ty * 4 + 0][kk];
            const float a1 = Ws[ty * 4 + 1][kk];
            const float a2 = Ws[ty * 4 + 2][kk];
            const float a3 = Ws[ty * 4 + 3][kk];
            const float4 bv = *(const float4*)(&Xs[kk][tx * 4]);
            acc[0][0] += a0 * bv.x; acc[0][1] += a0 * bv.y; acc[0][2] += a0 * bv.z; acc[0][3] += a0 * bv.w;
            acc[1][0] += a1 * bv.x; acc[1][1] += a1 * bv.y; acc[1][2] += a1 * bv.z; acc[1][3] += a1 * bv.w;
            acc[2][0] += a2 * bv.x; acc[2][1] += a2 * bv.y; acc[2][2] += a2 * bv.z; acc[2][3] += a2 * bv.w;
            acc[3][0] += a3 * bv.x; acc[3][1] += a3 * bv.y; acc[3][2] += a3 * bv.z; acc[3][3] += a3 * bv.w;
        }
    }
}

// ---------------------------------------------------------------------------
// QKV projections: grid (8*36, B, 6). out[j][b, o, l] = sum_c w[j][o,c] x[b,c,l] + b[j][o]
// ---------------------------------------------------------------------------
__global__ __launch_bounds__(256)
void qkv_kernel(const float* __restrict__ modal1, const float* __restrict__ modal2,
                Six w, Six bias, float* __restrict__ out_base)
{
    const int j = blockIdx.z;
    const int z = blockIdx.y;
    const int mt = blockIdx.x / 36;
    const int nt = blockIdx.x - mt * 36;
    const int m0 = mt * TILE, n0 = nt * TILE;

    const float* X = ((j < 3) ? modal1 : modal2) + (long long)z * 256 * HW_N;
    const float* W = w.p[j];
    const float* B = bias.p[j];
    float* Y = out_base + (long long)j * (2LL * 512 * HW_N) + (long long)z * 512 * HW_N;

    __shared__ float Ws[TILE][KB + 4];
    __shared__ float Xs[KB][TILE];
    float acc[4][4] = {};

    gemm_tile_core(X, nullptr, 1 << 28, W, 256, HW_N, m0, n0, Ws, Xs, acc);

    const int tx = threadIdx.x & 15, ty = threadIdx.x >> 4;
    const int col = n0 + tx * 4;
#pragma unroll
    for (int i = 0; i < 4; ++i) {
        const int row = m0 + ty * 4 + i;
        const float bv = B[row];
        float4 o4 = make_float4(acc[i][0] + bv, acc[i][1] + bv, acc[i][2] + bv, acc[i][3] + bv);
        *(float4*)(Y + (long long)row * HW_N + col) = o4;
    }
}

// ---------------------------------------------------------------------------
// Flash cross-attention. grid (36 ltiles, 8 heads, B*2).
// dir 0: softmax(Q1^T K2) V2 -> o1 ; dir 1: softmax(Q2^T K1) V1 -> o2
// Conv layout [B,512,HW]: slice rows are head channels (d), cols are L.
// ---------------------------------------------------------------------------
__global__ __launch_bounds__(256)
void attn_kernel(const float* __restrict__ q1, const float* __restrict__ k1, const float* __restrict__ v1,
                 const float* __restrict__ q2, const float* __restrict__ k2, const float* __restrict__ v2,
                 float* __restrict__ o1, float* __restrict__ o2)
{
    const int lt = blockIdx.x;
    const int h = blockIdx.y;
    const int b = blockIdx.z >> 1;
    const int dir = blockIdx.z & 1;

    const float* Q = dir ? q2 : q1;
    const float* Kp = dir ? k1 : k2;
    const float* Vp = dir ? v1 : v2;
    float* O = dir ? o2 : o1;

    const long long base = ((long long)b * 512 + h * 64) * HW_N;
    Q += base; Kp += base; Vp += base; O += base;
    const int l0 = lt * 64;

    __shared__ __align__(16) float qs[64][64];
    __shared__ __align__(16) float ks[64][64];
    __shared__ __align__(16) float vs[64][64];

    const int tid = threadIdx.x;

    // load Q tile: qs[d][l]
#pragma unroll
    for (int i = 0; i < 4; ++i) {
        const int e = i * 1024 + tid * 4;
        const int r = e >> 6, c = e & 63;
        *(float4*)(&qs[r][c]) = *(const float4*)(Q + (long long)r * HW_N + l0 + c);
    }

    const int l = tid >> 2;        // query row within tile (0..63)
    const int sub = tid & 3;       // m-subrange owner (0..3)
    const int msub = sub * 16;

    float m_run = -1e30f, s_run = 0.f;
    float acc[64];
#pragma unroll
    for (int d = 0; d < 64; ++d) acc[d] = 0.f;

    for (int mt = 0; mt < 36; ++mt) {
        const int m0 = mt * 64;
        __syncthreads();
#pragma unroll
        for (int i = 0; i < 4; ++i) {
            const int e = i * 1024 + tid * 4;
            const int r = e >> 6, c = e & 63;
            *(float4*)(&ks[r][c]) = *(const float4*)(Kp + (long long)r * HW_N + m0 + c);
            *(float4*)(&vs[r][c]) = *(const float4*)(Vp + (long long)r * HW_N + m0 + c);
        }
        __syncthreads();

        float s[16];
#pragma unroll
        for (int jj = 0; jj < 16; ++jj) s[jj] = 0.f;
#pragma unroll
        for (int d = 0; d < 64; ++d) {
            const float qv = qs[d][l];
            const float4* kr = (const float4*)(&ks[d][msub]);
            const float4 k0 = kr[0], k1v = kr[1], k2v = kr[2], k3v = kr[3];
            s[0]  += qv * k0.x;  s[1]  += qv * k0.y;  s[2]  += qv * k0.z;  s[3]  += qv * k0.w;
            s[4]  += qv * k1v.x; s[5]  += qv * k1v.y; s[6]  += qv * k1v.z; s[7]  += qv * k1v.w;
            s[8]  += qv * k2v.x; s[9]  += qv * k2v.y; s[10] += qv * k2v.z; s[11] += qv * k2v.w;
            s[12] += qv * k3v.x; s[13] += qv * k3v.y; s[14] += qv * k3v.z; s[15] += qv * k3v.w;
        }
        float tmax = -1e30f;
#pragma unroll
        for (int jj = 0; jj < 16; ++jj) { s[jj] *= 0.125f; tmax = fmaxf(tmax, s[jj]); }
        tmax = fmaxf(tmax, __shfl_xor(tmax, 1, 64));
        tmax = fmaxf(tmax, __shfl_xor(tmax, 2, 64));
        const float m_new = fmaxf(m_run, tmax);
        const float resc = __expf(m_run - m_new);
        float p[16];
        float psum = 0.f;
#pragma unroll
        for (int jj = 0; jj < 16; ++jj) { p[jj] = __expf(s[jj] - m_new); psum += p[jj]; }
        psum += __shfl_xor(psum, 1, 64);
        psum += __shfl_xor(psum, 2, 64);
        s_run = s_run * resc + psum;
        m_run = m_new;
#pragma unroll
        for (int d = 0; d < 64; ++d) {
            const float4* vr = (const float4*)(&vs[d][msub]);
            const float4 v0 = vr[0], v1v = vr[1], v2v = vr[2], v3v = vr[3];
            float part = p[0]  * v0.x  + p[1]  * v0.y  + p[2]  * v0.z  + p[3]  * v0.w
                       + p[4]  * v1v.x + p[5]  * v1v.y + p[6]  * v1v.z + p[7]  * v1v.w
                       + p[8]  * v2v.x + p[9]  * v2v.y + p[10] * v2v.z + p[11] * v2v.w
                       + p[12] * v3v.x + p[13] * v3v.y + p[14] * v3v.z + p[15] * v3v.w;
            acc[d] = acc[d] * resc + part;
        }
    }

    const float inv = 1.f / s_run;
#pragma unroll
    for (int d = 0; d < 64; ++d) {
        float tot = acc[d];
        tot += __shfl_xor(tot, 1, 64);
        tot += __shfl_xor(tot, 2, 64);
        if ((d >> 4) == sub) O[(long long)d * HW_N + l0 + l] = tot * inv;
    }
}

// ---------------------------------------------------------------------------
// Output projection + residual: grid (4*36, B, 2 dirs)
// mpre[dir][b,o,l] = modal_feat[b,o,l] + sum_c wo[o,c]*oat[dir][b,c,l] + bo[o]
// ---------------------------------------------------------------------------
__global__ __launch_bounds__(256)
void cross_kernel(const float* __restrict__ oat0, const float* __restrict__ oat1,
                  Six w, Six bias, Six resid,
                  float* __restrict__ mpre0, float* __restrict__ mpre1)
{
    const int dir = blockIdx.z;
    const int z = blockIdx.y;
    const int mt = blockIdx.x / 36;
    const int nt = blockIdx.x - mt * 36;
    const int m0 = mt * TILE, n0 = nt * TILE;

    const float* X = (dir ? oat1 : oat0) + (long long)z * 512 * HW_N;
    const float* W = w.p[dir];
    const float* B = bias.p[dir];
    const float* R = resid.p[dir] + (long long)z * 256 * HW_N;
    float* Y = (dir ? mpre1 : mpre0) + (long long)z * 256 * HW_N;

    __shared__ float Ws[TILE][KB + 4];
    __shared__ float Xs[KB][TILE];
    float acc[4][4] = {};

    gemm_tile_core(X, nullptr, 1 << 28, W, 512, HW_N, m0, n0, Ws, Xs, acc);

    const int tx = threadIdx.x & 15, ty = threadIdx.x >> 4;
    const int col = n0 + tx * 4;
#pragma unroll
    for (int i = 0; i < 4; ++i) {
        const int row = m0 + ty * 4 + i;
        const float bv = B[row];
        const float4 r4 = *(const float4*)(R + (long long)row * HW_N + col);
        float4 o4 = make_float4(acc[i][0] + bv + r4.x, acc[i][1] + bv + r4.y,
                                acc[i][2] + bv + r4.z, acc[i][3] + bv + r4.w);
        *(float4*)(Y + (long long)row * HW_N + col) = o4;
    }
}

// ---------------------------------------------------------------------------
// Channel LayerNorm (over C=256) per spatial position. grid (36, B, 2 dirs)
// ---------------------------------------------------------------------------
__global__ __launch_bounds__(256)
void ln_kernel(const float* __restrict__ src1, const float* __restrict__ src2,
               const float* __restrict__ g1, const float* __restrict__ b1,
               const float* __restrict__ g2, const float* __restrict__ b2,
               float* __restrict__ dst1, float* __restrict__ dst2)
{
    const int l0 = blockIdx.x * 64;
    const int b = blockIdx.y;
    const int dir = blockIdx.z;
    const float* src = dir ? src2 : src1;
    const float* g = dir ? g2 : g1;
    const float* bb = dir ? b2 : b1;
    float* dst = dir ? dst2 : dst1;
    const long long base = (long long)b * 256 * HW_N + l0;

    const int lc = threadIdx.x & 63;
    const int cg = threadIdx.x >> 6;

    float sum = 0.f, sq = 0.f;
    for (int c = cg * 64; c < cg * 64 + 64; ++c) {
        const float v = src[base + (long long)c * HW_N + lc];
        sum += v; sq += v * v;
    }
    __shared__ float rsum[4][64], rsq[4][64];
    __shared__ float smean[64], srstd[64];
    rsum[cg][lc] = sum; rsq[cg][lc] = sq;
    __syncthreads();
    if (cg == 0) {
        const float s = rsum[0][lc] + rsum[1][lc] + rsum[2][lc] + rsum[3][lc];
        const float q = rsq[0][lc] + rsq[1][lc] + rsq[2][lc] + rsq[3][lc];
        const float mean = s * (1.f / 256.f);
        const float var = q * (1.f / 256.f) - mean * mean;
        smean[lc] = mean;
        srstd[lc] = rsqrtf(var + EPS_F);
    }
    __syncthreads();
    const float mean = smean[lc], rstd = srstd[lc];
    for (int c = cg * 64; c < cg * 64 + 64; ++c) {
        const long long idx = base + (long long)c * HW_N + lc;
        dst[idx] = (src[idx] - mean) * rstd * g[c] + bb[c];
    }
}

// ---------------------------------------------------------------------------
// Fusion conv (concat over K) + BatchNorm(eval) + ReLU. grid (4*36, B)
// ---------------------------------------------------------------------------
__global__ __launch_bounds__(256)
void fuse_kernel(const float* __restrict__ mln0, const float* __restrict__ mln1,
                 const float* __restrict__ wf, const float* __restrict__ bf,
                 const float* __restrict__ bn_mean, const float* __restrict__ bn_var,
                 const float* __restrict__ bn_g, const float* __restrict__ bn_b,
                 float* __restrict__ out)
{
    const int z = blockIdx.y;
    const int mt = blockIdx.x / 36;
    const int nt = blockIdx.x - mt * 36;
    const int m0 = mt * TILE, n0 = nt * TILE;

    const float* X1 = mln0 + (long long)z * 256 * HW_N;
    const float* X2 = mln1 + (long long)z * 256 * HW_N;
    float* Y = out + (long long)z * 256 * HW_N;

    __shared__ float Ws[TILE][KB + 4];
    __shared__ float Xs[KB][TILE];
    float acc[4][4] = {};

    gemm_tile_core(X1, X2, 256, wf, 512, HW_N, m0, n0, Ws, Xs, acc);

    const int tx = threadIdx.x & 15, ty = threadIdx.x >> 4;
    const int col = n0 + tx * 4;
#pragma unroll
    for (int i = 0; i < 4; ++i) {
        const int row = m0 + ty * 4 + i;
        const float bv = bf[row];
        const float rstd = rsqrtf(bn_var[row] + EPS_F);
        const float sc = bn_g[row] * rstd;
        const float sh = bn_b[row] - bn_mean[row] * sc;
        float vals[4];
#pragma unroll
        for (int jj = 0; jj < 4; ++jj)
            vals[jj] = fmaxf((acc[i][jj] + bv) * sc + sh, 0.f);
        *(float4*)(Y + (long long)row * HW_N + col) =
            make_float4(vals[0], vals[1], vals[2], vals[3]);
    }
}

// ---------------------------------------------------------------------------
extern "C" void kernel_launch(void* const* d_in, const int* in_sizes, int n_in,
                              void* d_out, int out_size, void* d_ws, size_t ws_size,
                              hipStream_t stream)
{
    (void)in_sizes; (void)n_in; (void)out_size; (void)ws_size;

    const float* modal1 = (const float*)d_in[0];
    const float* modal2 = (const float*)d_in[1];

    Six wqkv, bqkv;
    for (int j = 0; j < 6; ++j) {
        wqkv.p[j] = (const float*)d_in[2 + 2 * j];
        bqkv.p[j] = (const float*)d_in[3 + 2 * j];
    }
    const float* wo1 = (const float*)d_in[14];
    const float* bo1 = (const float*)d_in[15];
    const float* wo2 = (const float*)d_in[16];
    const float* bo2 = (const float*)d_in[17];
    const float* ln1_g = (const float*)d_in[18];
    const float* ln1_b = (const float*)d_in[19];
    const float* ln2_g = (const float*)d_in[20];
    const float* ln2_b = (const float*)d_in[21];
    const float* wf = (const float*)d_in[22];
    const float* bf = (const float*)d_in[23];
    const float* bn_g = (const float*)d_in[24];
    const float* bn_b = (const float*)d_in[25];
    const float* bn_mean = (const float*)d_in[26];
    const float* bn_var = (const float*)d_in[27];

    float* ws = (float*)d_ws;
    const long long SZ512 = 2LL * 512 * HW_N;   // per qkv buffer (both batches)
    const long long SZ256 = 2LL * 256 * HW_N;

    float* qkvb = ws;                            // 6 buffers of SZ512
    float* oat0 = ws + 6 * SZ512;
    float* oat1 = ws + 7 * SZ512;
    // reuse q1/k1 regions (dead after attention) for LN intermediates
    float* mpre0 = ws;                           // overlays qkv[0]
    float* mpre1 = ws + SZ256;
    float* mln0 = ws + 2 * SZ256;                // overlays qkv[1]
    float* mln1 = ws + 3 * SZ256;

    // 1) QKV projections (6 GEMMs in one launch)
    qkv_kernel<<<dim3(8 * 36, 2, 6), 256, 0, stream>>>(modal1, modal2, wqkv, bqkv, qkvb);

    // 2) bidirectional flash cross-attention
    attn_kernel<<<dim3(36, 8, 4), 256, 0, stream>>>(
        qkvb + 0 * SZ512, qkvb + 1 * SZ512, qkvb + 2 * SZ512,
        qkvb + 3 * SZ512, qkvb + 4 * SZ512, qkvb + 5 * SZ512,
        oat0, oat1);

    // 3) output projections + residual
    Six wo, bo, resid;
    wo.p[0] = wo1; wo.p[1] = wo2;
    bo.p[0] = bo1; bo.p[1] = bo2;
    resid.p[0] = modal1; resid.p[1] = modal2;
    for (int j = 2; j < 6; ++j) { wo.p[j] = nullptr; bo.p[j] = nullptr; resid.p[j] = nullptr; }
    cross_kernel<<<dim3(4 * 36, 2, 2), 256, 0, stream>>>(oat0, oat1, wo, bo, resid, mpre0, mpre1);

    // 4) channel LayerNorm
    ln_kernel<<<dim3(36, 2, 2), 256, 0, stream>>>(mpre0, mpre1, ln1_g, ln1_b, ln2_g, ln2_b, mln0, mln1);

    // 5) fusion conv + BN + ReLU -> d_out
    fuse_kernel<<<dim3(4 * 36, 2), 256, 0, stream>>>(mln0, mln1, wf, bf,
                                                     bn_mean, bn_var, bn_g, bn_b,
                                                     (float*)d_out);
}

// Round 2
// 360.410 us; speedup vs baseline: 3.2150x; 3.2150x over previous
//
#include <hip/hip_runtime.h>
#include <hip/hip_bf16.h>

#define HW_N 2304
#define EPS_F 1e-5f

constexpr int TILE = 64;
constexpr int KB = 16;

typedef float f32x4 __attribute__((ext_vector_type(4)));
typedef short short8v __attribute__((ext_vector_type(8)));
typedef __bf16 bf16x8 __attribute__((ext_vector_type(8)));
typedef unsigned short u16;

struct Six { const float* p[6]; };
struct OutP { u16* q[2]; u16* k[2]; u16* v[2]; };

__device__ __forceinline__ f32x4 mfma_bf16(bf16x8 a, bf16x8 b, f32x4 c) {
    return __builtin_amdgcn_mfma_f32_16x16x32_bf16(a, b, c, 0, 0, 0);
}
__device__ __forceinline__ bf16x8 ld8(const void* p) {
    return __builtin_bit_cast(bf16x8, *(const short8v*)p);
}
__device__ __forceinline__ unsigned short bfbits(float v) {
    return __builtin_bit_cast(unsigned short, __float2bfloat16(v));
}
__device__ __forceinline__ unsigned pack2(float lo, float hi) {
    return (unsigned)bfbits(lo) | ((unsigned)bfbits(hi) << 16);
}
__device__ __forceinline__ float max4(f32x4 v) {
    return fmaxf(fmaxf(v.x, v.y), fmaxf(v.z, v.w));
}
__device__ __forceinline__ float sum4(f32x4 v) {
    return (v.x + v.y) + (v.z + v.w);
}

// ---------------------------------------------------------------------------
// Generic 64x64 fp32 GEMM tile core (unchanged from round 0)
// ---------------------------------------------------------------------------
__device__ __forceinline__ void gemm_tile_core(
    const float* __restrict__ x1, const float* __restrict__ x2, int K1,
    const float* __restrict__ W, int K, int N, int m0, int n0,
    float (*Ws)[KB + 4], float (*Xs)[TILE], float acc[4][4])
{
    const int tid = threadIdx.x;
    const int wr = tid >> 2;
    const int wc = (tid & 3) * 4;
    const int xr = tid >> 4;
    const int xc = (tid & 15) * 4;
    const int tx = tid & 15, ty = tid >> 4;

    for (int kb = 0; kb < K; kb += KB) {
        __syncthreads();
        *(float4*)(&Ws[wr][wc]) =
            *(const float4*)(W + (long long)(m0 + wr) * K + kb + wc);
        {
            const int k = kb + xr;
            const float* src = (k < K1) ? (x1 + (long long)k * N)
                                        : (x2 + (long long)(k - K1) * N);
            *(float4*)(&Xs[xr][xc]) = *(const float4*)(src + n0 + xc);
        }
        __syncthreads();
#pragma unroll
        for (int kk = 0; kk < KB; ++kk) {
            const float a0 = Ws[ty * 4 + 0][kk];
            const float a1 = Ws[ty * 4 + 1][kk];
            const float a2 = Ws[ty * 4 + 2][kk];
            const float a3 = Ws[ty * 4 + 3][kk];
            const float4 bv = *(const float4*)(&Xs[kk][tx * 4]);
            acc[0][0] += a0 * bv.x; acc[0][1] += a0 * bv.y; acc[0][2] += a0 * bv.z; acc[0][3] += a0 * bv.w;
            acc[1][0] += a1 * bv.x; acc[1][1] += a1 * bv.y; acc[1][2] += a1 * bv.z; acc[1][3] += a1 * bv.w;
            acc[2][0] += a2 * bv.x; acc[2][1] += a2 * bv.y; acc[2][2] += a2 * bv.z; acc[2][3] += a2 * bv.w;
            acc[3][0] += a3 * bv.x; acc[3][1] += a3 * bv.y; acc[3][2] += a3 * bv.z; acc[3][3] += a3 * bv.w;
        }
    }
}

// ---------------------------------------------------------------------------
// QKV projections, now writing bf16.
// kind 0 (q): transposed [b][h][l][d], scaled by 0.125*log2e (fold softmax scale)
// kind 1 (k): transposed [b][h][l][d]
// kind 2 (v): conv layout [b][512][HW]
// ---------------------------------------------------------------------------
__global__ __launch_bounds__(256)
void qkv_kernel(const float* __restrict__ modal1, const float* __restrict__ modal2,
                Six w, Six bias, OutP outp)
{
    const int j = blockIdx.z;
    const int z = blockIdx.y;
    const int mt = blockIdx.x / 36;            // head index (64 rows per head)
    const int nt = blockIdx.x - mt * 36;
    const int m0 = mt * TILE, n0 = nt * TILE;

    const float* X = ((j < 3) ? modal1 : modal2) + (long long)z * 256 * HW_N;
    const float* W = w.p[j];
    const float* B = bias.p[j];
    const int kind = j % 3;
    const int which = j / 3;

    __shared__ float Ws[TILE][KB + 4];
    __shared__ float Xs[KB][TILE];
    float acc[4][4] = {};

    gemm_tile_core(X, nullptr, 1 << 28, W, 256, HW_N, m0, n0, Ws, Xs, acc);

    const int tx = threadIdx.x & 15, ty = threadIdx.x >> 4;
    float bv[4];
#pragma unroll
    for (int i = 0; i < 4; ++i) bv[i] = B[m0 + ty * 4 + i];

    if (kind == 2) {
        u16* Vb = outp.v[which] + (long long)z * 512 * HW_N;
        const int col = n0 + tx * 4;
#pragma unroll
        for (int i = 0; i < 4; ++i) {
            ushort4 pk;
            pk.x = bfbits(acc[i][0] + bv[i]);
            pk.y = bfbits(acc[i][1] + bv[i]);
            pk.z = bfbits(acc[i][2] + bv[i]);
            pk.w = bfbits(acc[i][3] + bv[i]);
            *(ushort4*)(Vb + (long long)(m0 + ty * 4 + i) * HW_N + col) = pk;
        }
    } else {
        u16* T = (kind == 0) ? outp.q[which] : outp.k[which];
        const float s = (kind == 0) ? 0.1803368801111204f : 1.0f;  // 0.125*log2(e)
        T += ((long long)(z * 8 + mt) * HW_N) * 64;
#pragma unroll
        for (int jj = 0; jj < 4; ++jj) {
            const int l = n0 + tx * 4 + jj;
            ushort4 pk;
            pk.x = bfbits((acc[0][jj] + bv[0]) * s);
            pk.y = bfbits((acc[1][jj] + bv[1]) * s);
            pk.z = bfbits((acc[2][jj] + bv[2]) * s);
            pk.w = bfbits((acc[3][jj] + bv[3]) * s);
            *(ushort4*)(T + (long long)l * 64 + ty * 4) = pk;
        }
    }
}

// ---------------------------------------------------------------------------
// MFMA flash cross-attention.
// Q,K transposed bf16 [b][h][2304][64]; V conv bf16 [b][512][2304].
// Block = 64 queries (4 waves x 16), loop over 36 key-tiles of 64.
// S^T = K*Q (per-lane P is column-local), O^T = V*P.
// ---------------------------------------------------------------------------
__global__ __launch_bounds__(256)
void attn_mfma_kernel(const u16* __restrict__ qt0, const u16* __restrict__ kt0,
                      const u16* __restrict__ v0b,
                      const u16* __restrict__ qt1, const u16* __restrict__ kt1,
                      const u16* __restrict__ v1b,
                      float* __restrict__ oat0, float* __restrict__ oat1)
{
    // XCD-friendly remap: each XCD gets 4 heads x 36 ltiles of one (b,dir)
    const int flat = blockIdx.x;
    const int virt = (flat & 7) * 144 + (flat >> 3);
    const int lt = virt % 36;
    const int h = (virt / 36) & 7;
    const int zz = virt / 288;
    const int b = zz >> 1, dir = zz & 1;

    const u16* QT = dir ? qt1 : qt0;
    const u16* KT = dir ? kt0 : kt1;   // cross: dir0 pairs Q1 with K2/V2
    const u16* V  = dir ? v0b : v1b;
    float* O = dir ? oat1 : oat0;

    const long long bh = (long long)(b * 8 + h);
    const u16* Qb = QT + bh * HW_N * 64;
    const u16* Kb = KT + bh * HW_N * 64;
    const u16* Vb = V + ((long long)b * 512 + h * 64) * HW_N;
    float* Ob = O + ((long long)b * 512 + h * 64) * HW_N;

    const int tid = threadIdx.x;
    const int w = tid >> 6, lane = tid & 63;
    const int l16 = lane & 15, lg = lane >> 4;
    const int l0 = lt * 64;

    __shared__ u16 Ks[64 * 64];
    __shared__ u16 Vs[64 * 64];
    __shared__ u16 Ps[4][16 * 72];     // per-wave P buffer, padded rows (144B)

    // Q fragments (kept in registers for the whole block)
    bf16x8 qf0, qf1;
    {
        const u16* qrow = Qb + (long long)(l0 + 16 * w + l16) * 64 + 8 * lg;
        qf0 = ld8(qrow);
        qf1 = ld8(qrow + 32);
    }

    f32x4 acc0 = {0.f, 0.f, 0.f, 0.f}, acc1 = acc0, acc2 = acc0, acc3 = acc0;
    float m_run = -1e30f, s_run = 0.f;

    const int rsub = lane >> 3;          // 0..7
    const int csub = (lane & 7) * 8;     // element offset within 64-wide row
    const int r0 = 16 * w + rsub, r1 = r0 + 8;
    const int swz0 = (csub * 2) ^ ((r0 & 7) << 4);
    const int swz1 = (csub * 2) ^ ((r1 & 7) << 4);
    const int cb0 = (16 * lg) ^ ((l16 & 7) << 4);          // frag byte col, k=0..31
    const int cb1 = (16 * lg + 64) ^ ((l16 & 7) << 4);     // k=32..63

    // staging registers
    short8v ka, kb2, va, vb2;
    {
        const u16* kbase = Kb + (long long)(16 * w) * 64;
        ka  = *(const short8v*)(kbase + (long long)rsub * 64 + csub);
        kb2 = *(const short8v*)(kbase + (long long)(8 + rsub) * 64 + csub);
        const u16* vbase = Vb + (long long)(16 * w + rsub) * HW_N + csub;
        va  = *(const short8v*)(vbase);
        vb2 = *(const short8v*)(vbase + 8LL * HW_N);
    }

    u16* Pw = &Ps[w][0];
    char* prow = (char*)Pw + 144 * l16;

    for (int t = 0; t < 36; ++t) {
        if (t) __syncthreads();
        // commit staged tile to LDS (swizzled)
        *(short8v*)((char*)Ks + r0 * 128 + swz0) = ka;
        *(short8v*)((char*)Ks + r1 * 128 + swz1) = kb2;
        *(short8v*)((char*)Vs + r0 * 128 + swz0) = va;
        *(short8v*)((char*)Vs + r1 * 128 + swz1) = vb2;
        __syncthreads();
        // issue next tile's global loads (latency hides under compute)
        if (t + 1 < 36) {
            const int m0 = (t + 1) * 64;
            const u16* kbase = Kb + (long long)(m0 + 16 * w) * 64;
            ka  = *(const short8v*)(kbase + (long long)rsub * 64 + csub);
            kb2 = *(const short8v*)(kbase + (long long)(8 + rsub) * 64 + csub);
            const u16* vbase = Vb + (long long)(16 * w + rsub) * HW_N + m0 + csub;
            va  = *(const short8v*)(vbase);
            vb2 = *(const short8v*)(vbase + 8LL * HW_N);
        }

        // ---- QK^T: S^T tiles [16m x 16l], m-tiles 0..3
        const char* kb_ = (const char*)Ks + l16 * 128;
        f32x4 st0 = {0.f,0.f,0.f,0.f}, st1 = st0, st2 = st0, st3 = st0;
        st0 = mfma_bf16(ld8(kb_ + 0 * 2048 + cb0), qf0, st0);
        st0 = mfma_bf16(ld8(kb_ + 0 * 2048 + cb1), qf1, st0);
        st1 = mfma_bf16(ld8(kb_ + 1 * 2048 + cb0), qf0, st1);
        st1 = mfma_bf16(ld8(kb_ + 1 * 2048 + cb1), qf1, st1);
        st2 = mfma_bf16(ld8(kb_ + 2 * 2048 + cb0), qf0, st2);
        st2 = mfma_bf16(ld8(kb_ + 2 * 2048 + cb1), qf1, st2);
        st3 = mfma_bf16(ld8(kb_ + 3 * 2048 + cb0), qf0, st3);
        st3 = mfma_bf16(ld8(kb_ + 3 * 2048 + cb1), qf1, st3);

        // ---- online softmax (values are already in log2 domain)
        float mx = fmaxf(fmaxf(max4(st0), max4(st1)), fmaxf(max4(st2), max4(st3)));
        mx = fmaxf(mx, __shfl_xor(mx, 16, 64));
        mx = fmaxf(mx, __shfl_xor(mx, 32, 64));
        const float m_new = fmaxf(m_run, mx);
        const float alpha = exp2f(m_run - m_new);

        f32x4 p0, p1, p2, p3;
        p0.x = exp2f(st0.x - m_new); p0.y = exp2f(st0.y - m_new);
        p0.z = exp2f(st0.z - m_new); p0.w = exp2f(st0.w - m_new);
        p1.x = exp2f(st1.x - m_new); p1.y = exp2f(st1.y - m_new);
        p1.z = exp2f(st1.z - m_new); p1.w = exp2f(st1.w - m_new);
        p2.x = exp2f(st2.x - m_new); p2.y = exp2f(st2.y - m_new);
        p2.z = exp2f(st2.z - m_new); p2.w = exp2f(st2.w - m_new);
        p3.x = exp2f(st3.x - m_new); p3.y = exp2f(st3.y - m_new);
        p3.z = exp2f(st3.z - m_new); p3.w = exp2f(st3.w - m_new);

        float psum = sum4(p0) + sum4(p1) + sum4(p2) + sum4(p3);
        psum += __shfl_xor(psum, 16, 64);
        psum += __shfl_xor(psum, 32, 64);
        s_run = s_run * alpha + psum;
        m_run = m_new;
        acc0 *= alpha; acc1 *= alpha; acc2 *= alpha; acc3 *= alpha;

        // ---- pack P to bf16 in per-wave LDS [16 l][64 m] (+8 pad)
        *(unsigned*)(prow + 8 * lg + 0)       = pack2(p0.x, p0.y);
        *(unsigned*)(prow + 8 * lg + 4)       = pack2(p0.z, p0.w);
        *(unsigned*)(prow + 8 * lg + 32)      = pack2(p1.x, p1.y);
        *(unsigned*)(prow + 8 * lg + 36)      = pack2(p1.z, p1.w);
        *(unsigned*)(prow + 8 * lg + 64)      = pack2(p2.x, p2.y);
        *(unsigned*)(prow + 8 * lg + 68)      = pack2(p2.z, p2.w);
        *(unsigned*)(prow + 8 * lg + 96)      = pack2(p3.x, p3.y);
        *(unsigned*)(prow + 8 * lg + 100)     = pack2(p3.z, p3.w);

        // ---- PV: O^T tiles [16dv x 16l]
        bf16x8 pf0 = ld8(prow + 16 * lg);
        bf16x8 pf1 = ld8(prow + 64 + 16 * lg);
        const char* vb_ = (const char*)Vs + l16 * 128;
        acc0 = mfma_bf16(ld8(vb_ + 0 * 2048 + cb0), pf0, acc0);
        acc0 = mfma_bf16(ld8(vb_ + 0 * 2048 + cb1), pf1, acc0);
        acc1 = mfma_bf16(ld8(vb_ + 1 * 2048 + cb0), pf0, acc1);
        acc1 = mfma_bf16(ld8(vb_ + 1 * 2048 + cb1), pf1, acc1);
        acc2 = mfma_bf16(ld8(vb_ + 2 * 2048 + cb0), pf0, acc2);
        acc2 = mfma_bf16(ld8(vb_ + 2 * 2048 + cb1), pf1, acc2);
        acc3 = mfma_bf16(ld8(vb_ + 3 * 2048 + cb0), pf0, acc3);
        acc3 = mfma_bf16(ld8(vb_ + 3 * 2048 + cb1), pf1, acc3);
    }

    const float inv = 1.0f / s_run;
    float* obase = Ob + l0 + 16 * w + l16;
    const int dvb = 4 * lg;
#define OSTORE(T4, A) \
    obase[(long long)((T4)*16 + dvb + 0) * HW_N] = A.x * inv; \
    obase[(long long)((T4)*16 + dvb + 1) * HW_N] = A.y * inv; \
    obase[(long long)((T4)*16 + dvb + 2) * HW_N] = A.z * inv; \
    obase[(long long)((T4)*16 + dvb + 3) * HW_N] = A.w * inv;
    OSTORE(0, acc0) OSTORE(1, acc1) OSTORE(2, acc2) OSTORE(3, acc3)
#undef OSTORE
}

// ---------------------------------------------------------------------------
// Output projection + residual (fp32, unchanged)
// ---------------------------------------------------------------------------
__global__ __launch_bounds__(256)
void cross_kernel(const float* __restrict__ oat0, const float* __restrict__ oat1,
                  Six w, Six bias, Six resid,
                  float* __restrict__ mpre0, float* __restrict__ mpre1)
{
    const int dir = blockIdx.z;
    const int z = blockIdx.y;
    const int mt = blockIdx.x / 36;
    const int nt = blockIdx.x - mt * 36;
    const int m0 = mt * TILE, n0 = nt * TILE;

    const float* X = (dir ? oat1 : oat0) + (long long)z * 512 * HW_N;
    const float* W = w.p[dir];
    const float* B = bias.p[dir];
    const float* R = resid.p[dir] + (long long)z * 256 * HW_N;
    float* Y = (dir ? mpre1 : mpre0) + (long long)z * 256 * HW_N;

    __shared__ float Ws[TILE][KB + 4];
    __shared__ float Xs[KB][TILE];
    float acc[4][4] = {};

    gemm_tile_core(X, nullptr, 1 << 28, W, 512, HW_N, m0, n0, Ws, Xs, acc);

    const int tx = threadIdx.x & 15, ty = threadIdx.x >> 4;
    const int col = n0 + tx * 4;
#pragma unroll
    for (int i = 0; i < 4; ++i) {
        const int row = m0 + ty * 4 + i;
        const float bv = B[row];
        const float4 r4 = *(const float4*)(R + (long long)row * HW_N + col);
        float4 o4 = make_float4(acc[i][0] + bv + r4.x, acc[i][1] + bv + r4.y,
                                acc[i][2] + bv + r4.z, acc[i][3] + bv + r4.w);
        *(float4*)(Y + (long long)row * HW_N + col) = o4;
    }
}

// ---------------------------------------------------------------------------
// Channel LayerNorm (unchanged)
// ---------------------------------------------------------------------------
__global__ __launch_bounds__(256)
void ln_kernel(const float* __restrict__ src1, const float* __restrict__ src2,
               const float* __restrict__ g1, const float* __restrict__ b1,
               const float* __restrict__ g2, const float* __restrict__ b2,
               float* __restrict__ dst1, float* __restrict__ dst2)
{
    const int l0 = blockIdx.x * 64;
    const int b = blockIdx.y;
    const int dir = blockIdx.z;
    const float* src = dir ? src2 : src1;
    const float* g = dir ? g2 : g1;
    const float* bb = dir ? b2 : b1;
    float* dst = dir ? dst2 : dst1;
    const long long base = (long long)b * 256 * HW_N + l0;

    const int lc = threadIdx.x & 63;
    const int cg = threadIdx.x >> 6;

    float sum = 0.f, sq = 0.f;
    for (int c = cg * 64; c < cg * 64 + 64; ++c) {
        const float v = src[base + (long long)c * HW_N + lc];
        sum += v; sq += v * v;
    }
    __shared__ float rsum[4][64], rsq[4][64];
    __shared__ float smean[64], srstd[64];
    rsum[cg][lc] = sum; rsq[cg][lc] = sq;
    __syncthreads();
    if (cg == 0) {
        const float s = rsum[0][lc] + rsum[1][lc] + rsum[2][lc] + rsum[3][lc];
        const float q = rsq[0][lc] + rsq[1][lc] + rsq[2][lc] + rsq[3][lc];
        const float mean = s * (1.f / 256.f);
        const float var = q * (1.f / 256.f) - mean * mean;
        smean[lc] = mean;
        srstd[lc] = rsqrtf(var + EPS_F);
    }
    __syncthreads();
    const float mean = smean[lc], rstd = srstd[lc];
    for (int c = cg * 64; c < cg * 64 + 64; ++c) {
        const long long idx = base + (long long)c * HW_N + lc;
        dst[idx] = (src[idx] - mean) * rstd * g[c] + bb[c];
    }
}

// ---------------------------------------------------------------------------
// Fusion conv (concat over K) + BatchNorm(eval) + ReLU (unchanged)
// ---------------------------------------------------------------------------
__global__ __launch_bounds__(256)
void fuse_kernel(const float* __restrict__ mln0, const float* __restrict__ mln1,
                 const float* __restrict__ wf, const float* __restrict__ bf,
                 const float* __restrict__ bn_mean, const float* __restrict__ bn_var,
                 const float* __restrict__ bn_g, const float* __restrict__ bn_b,
                 float* __restrict__ out)
{
    const int z = blockIdx.y;
    const int mt = blockIdx.x / 36;
    const int nt = blockIdx.x - mt * 36;
    const int m0 = mt * TILE, n0 = nt * TILE;

    const float* X1 = mln0 + (long long)z * 256 * HW_N;
    const float* X2 = mln1 + (long long)z * 256 * HW_N;
    float* Y = out + (long long)z * 256 * HW_N;

    __shared__ float Ws[TILE][KB + 4];
    __shared__ float Xs[KB][TILE];
    float acc[4][4] = {};

    gemm_tile_core(X1, X2, 256, wf, 512, HW_N, m0, n0, Ws, Xs, acc);

    const int tx = threadIdx.x & 15, ty = threadIdx.x >> 4;
    const int col = n0 + tx * 4;
#pragma unroll
    for (int i = 0; i < 4; ++i) {
        const int row = m0 + ty * 4 + i;
        const float bvv = bf[row];
        const float rstd = rsqrtf(bn_var[row] + EPS_F);
        const float sc = bn_g[row] * rstd;
        const float sh = bn_b[row] - bn_mean[row] * sc;
        float vals[4];
#pragma unroll
        for (int jj = 0; jj < 4; ++jj)
            vals[jj] = fmaxf((acc[i][jj] + bvv) * sc + sh, 0.f);
        *(float4*)(Y + (long long)row * HW_N + col) =
            make_float4(vals[0], vals[1], vals[2], vals[3]);
    }
}

// ---------------------------------------------------------------------------
extern "C" void kernel_launch(void* const* d_in, const int* in_sizes, int n_in,
                              void* d_out, int out_size, void* d_ws, size_t ws_size,
                              hipStream_t stream)
{
    (void)in_sizes; (void)n_in; (void)out_size; (void)ws_size;

    const float* modal1 = (const float*)d_in[0];
    const float* modal2 = (const float*)d_in[1];

    Six wqkv, bqkv;
    for (int j = 0; j < 6; ++j) {
        wqkv.p[j] = (const float*)d_in[2 + 2 * j];
        bqkv.p[j] = (const float*)d_in[3 + 2 * j];
    }
    const float* wo1 = (const float*)d_in[14];
    const float* bo1 = (const float*)d_in[15];
    const float* wo2 = (const float*)d_in[16];
    const float* bo2 = (const float*)d_in[17];
    const float* ln1_g = (const float*)d_in[18];
    const float* ln1_b = (const float*)d_in[19];
    const float* ln2_g = (const float*)d_in[20];
    const float* ln2_b = (const float*)d_in[21];
    const float* wf = (const float*)d_in[22];
    const float* bf = (const float*)d_in[23];
    const float* bn_g = (const float*)d_in[24];
    const float* bn_b = (const float*)d_in[25];
    const float* bn_mean = (const float*)d_in[26];
    const float* bn_var = (const float*)d_in[27];

    char* ws = (char*)d_ws;
    const long long EL = 2LL * 512 * HW_N;     // 2359296 elements

    OutP outp;
    outp.q[0] = (u16*)(ws + EL * 0);
    outp.k[0] = (u16*)(ws + EL * 2);
    outp.v[0] = (u16*)(ws + EL * 4);
    outp.q[1] = (u16*)(ws + EL * 6);
    outp.k[1] = (u16*)(ws + EL * 8);
    outp.v[1] = (u16*)(ws + EL * 10);
    float* oat0 = (float*)(ws + EL * 12);
    float* oat1 = (float*)(ws + EL * 16);
    float* mpre0 = (float*)(ws + EL * 20);
    float* mpre1 = (float*)(ws + EL * 22);
    float* mln0  = (float*)(ws + EL * 24);
    float* mln1  = (float*)(ws + EL * 26);

    // 1) QKV projections -> bf16 (Q/K transposed, V conv layout)
    qkv_kernel<<<dim3(8 * 36, 2, 6), 256, 0, stream>>>(modal1, modal2, wqkv, bqkv, outp);

    // 2) MFMA flash cross-attention -> fp32 conv layout
    attn_mfma_kernel<<<dim3(36 * 8 * 4), 256, 0, stream>>>(
        outp.q[0], outp.k[0], outp.v[0],
        outp.q[1], outp.k[1], outp.v[1],
        oat0, oat1);

    // 3) output projections + residual
    Six wo, bo, resid;
    wo.p[0] = wo1; wo.p[1] = wo2;
    bo.p[0] = bo1; bo.p[1] = bo2;
    resid.p[0] = modal1; resid.p[1] = modal2;
    for (int j = 2; j < 6; ++j) { wo.p[j] = nullptr; bo.p[j] = nullptr; resid.p[j] = nullptr; }
    cross_kernel<<<dim3(4 * 36, 2, 2), 256, 0, stream>>>(oat0, oat1, wo, bo, resid, mpre0, mpre1);

    // 4) channel LayerNorm
    ln_kernel<<<dim3(36, 2, 2), 256, 0, stream>>>(mpre0, mpre1, ln1_g, ln1_b, ln2_g, ln2_b, mln0, mln1);

    // 5) fusion conv + BN + ReLU -> d_out
    fuse_kernel<<<dim3(4 * 36, 2), 256, 0, stream>>>(mln0, mln1, wf, bf,
                                                     bn_mean, bn_var, bn_g, bn_b,
                                                     (float*)d_out);
}

// Round 3
// 195.047 us; speedup vs baseline: 5.9408x; 1.8478x over previous
//
#include <hip/hip_runtime.h>
#include <hip/hip_bf16.h>

#define HW_N 2304
#define EPS_F 1e-5f
#define QSCALE 0.18033688011112043f   // 0.125 * log2(e)

typedef float f32x4 __attribute__((ext_vector_type(4)));
typedef short short8v __attribute__((ext_vector_type(8)));
typedef __bf16 bf16x8 __attribute__((ext_vector_type(8)));
typedef unsigned short u16;

__device__ __forceinline__ f32x4 mfma_bf16(bf16x8 a, bf16x8 b, f32x4 c) {
    return __builtin_amdgcn_mfma_f32_16x16x32_bf16(a, b, c, 0, 0, 0);
}
__device__ __forceinline__ bf16x8 ld8(const void* p) {
    return __builtin_bit_cast(bf16x8, *(const short8v*)p);
}
__device__ __forceinline__ unsigned short bfbits(float v) {
    return __builtin_bit_cast(unsigned short, __float2bfloat16(v));
}
__device__ __forceinline__ float b2f(u16 u) {
    unsigned x = (unsigned)u << 16;
    return __builtin_bit_cast(float, x);
}
__device__ __forceinline__ unsigned pack2(float lo, float hi) {
    return (unsigned)bfbits(lo) | ((unsigned)bfbits(hi) << 16);
}
__device__ __forceinline__ float max4(f32x4 v) {
    return fmaxf(fmaxf(v.x, v.y), fmaxf(v.z, v.w));
}
__device__ __forceinline__ float sum4(f32x4 v) {
    return (v.x + v.y) + (v.z + v.w);
}

// ---------------------------------------------------------------------------
// Prep: convert 9 weight matrices (all 131072 elements) fp32 -> bf16
// ---------------------------------------------------------------------------
struct WPtrs { const float* s[9]; u16* d[9]; };

__global__ __launch_bounds__(256)
void conv_w_kernel(WPtrs p)
{
    const int j = blockIdx.z;
    const float* s = p.s[j];
    u16* d = p.d[j];
    const int i = (blockIdx.x * 256 + threadIdx.x) * 4;
    const float4 v = *(const float4*)(s + i);
    ushort4 pk;
    pk.x = bfbits(v.x); pk.y = bfbits(v.y); pk.z = bfbits(v.z); pk.w = bfbits(v.w);
    *(ushort4*)(d + i) = pk;
}

// ---------------------------------------------------------------------------
// Prep: transpose modal feats [b][256][2304] fp32 -> [b][2304][256] bf16
// grid (36 l-tiles, 4 c-tiles, 4 = which*2+b)
// ---------------------------------------------------------------------------
__global__ __launch_bounds__(256)
void prep_modal_kernel(const float* __restrict__ m1, const float* __restrict__ m2,
                       u16* __restrict__ t1, u16* __restrict__ t2)
{
    const int l0 = blockIdx.x * 64, c0 = blockIdx.y * 64;
    const int which = blockIdx.z >> 1, b = blockIdx.z & 1;
    const float* src = (which ? m2 : m1) + ((long long)b * 256 + c0) * HW_N + l0;
    u16* dst = (which ? t2 : t1) + ((long long)b * HW_N + l0) * 256 + c0;

    __shared__ float tile[64][65];
    const int t = threadIdx.x;
    const int r = t >> 4, cq = (t & 15) * 4;
#pragma unroll
    for (int i = 0; i < 4; ++i) {
        const int row = r + i * 16;
        const float4 v = *(const float4*)(src + (long long)row * HW_N + cq);
        tile[row][cq + 0] = v.x; tile[row][cq + 1] = v.y;
        tile[row][cq + 2] = v.z; tile[row][cq + 3] = v.w;
    }
    __syncthreads();
#pragma unroll
    for (int i = 0; i < 4; ++i) {
        const int lr = r + i * 16;
        ushort4 pk;
        pk.x = bfbits(tile[cq + 0][lr]);
        pk.y = bfbits(tile[cq + 1][lr]);
        pk.z = bfbits(tile[cq + 2][lr]);
        pk.w = bfbits(tile[cq + 3][lr]);
        *(ushort4*)(dst + (long long)lr * 256 + cq) = pk;
    }
}

// ---------------------------------------------------------------------------
// Generic MFMA GEMM: Y[128m x 128n] = W[M,K](bf16) * X^T-rows, 4 waves.
// MODE 0: qkv  (K=256, X = modalT, epilogues: Q/K transposed bf16, V conv bf16)
// MODE 1: cross(K=512, X = oatT per-head, + residual, out fp32 transposed)
// MODE 2: fuse (K=512, X = concat mlnT, + BN + ReLU, out fp32 conv)
// ---------------------------------------------------------------------------
struct GArgs {
    const u16* W[6];
    const float* bias[6];
    const u16* X[2];
    const u16* R[2];
    u16* outQ[2]; u16* outK[2]; u16* outV[2];
    float* outT[2];
    float* outC;
    const float *bnm, *bnv, *bng, *bnb;
};

template<int MODE>
__global__ __launch_bounds__(256)
void gemm_mfma(GArgs g)
{
    constexpr int KD = (MODE == 0) ? 256 : 512;
    constexpr int NS = KD / 32;
    const int z = blockIdx.y;
    const int j = blockIdx.z;
    const int mt_b = blockIdx.x / 18;
    const int nt_b = blockIdx.x - mt_b * 18;
    const int m0 = mt_b * 128, n0 = nt_b * 128;

    const u16* Wb = g.W[(MODE == 2) ? 0 : j];
    const u16* Xb0 = (MODE == 0) ? g.X[(j < 3) ? 0 : 1]
                                 : ((MODE == 1) ? g.X[j] : nullptr);

    __shared__ u16 Als[4096];   // 8KB, fragment-order: chunk c = [row|k8] 16B
    __shared__ u16 Bls[4096];

    const int tid = threadIdx.x;
    const int w = tid >> 6, lane = tid & 63;
    const int l16 = lane & 15, lg = lane >> 4;

    // chunk c0 = tid -> tile row ar0, k-octet k8; chunk c1 = tid+256 -> row+64
    const int ar0 = (((tid >> 6) << 4) | (tid & 15));
    const int k8 = (tid >> 4) & 3;

    short8v sa0, sa1, sb0, sb1;

    auto stage = [&](int kb) {
        const int koff = kb + k8 * 8;
        sa0 = *(const short8v*)(Wb + (long long)(m0 + ar0) * KD + koff);
        sa1 = *(const short8v*)(Wb + (long long)(m0 + ar0 + 64) * KD + koff);
        if constexpr (MODE == 0) {
            const u16* p = Xb0 + ((long long)z * HW_N + n0 + ar0) * 256 + koff;
            sb0 = *(const short8v*)p;
            sb1 = *(const short8v*)(p + 64LL * 256);
        } else if constexpr (MODE == 1) {
            const int head = kb >> 6;
            const u16* p = Xb0 + (((long long)z * 8 + head) * HW_N + n0 + ar0) * 64 + (koff & 63);
            sb0 = *(const short8v*)p;
            sb1 = *(const short8v*)(p + 64LL * 64);
        } else {
            const u16* Xb = (kb < 256) ? g.X[0] : g.X[1];
            const u16* p = Xb + ((long long)z * HW_N + n0 + ar0) * 256 + (koff & 255);
            sb0 = *(const short8v*)p;
            sb1 = *(const short8v*)(p + 64LL * 256);
        }
    };

    f32x4 acc[4][4];
#pragma unroll
    for (int a = 0; a < 4; ++a)
#pragma unroll
        for (int b = 0; b < 4; ++b) acc[a][b] = f32x4{0.f, 0.f, 0.f, 0.f};

    stage(0);
    for (int s = 0; s < NS; ++s) {
        __syncthreads();
        *(short8v*)((char*)Als + tid * 16) = sa0;
        *(short8v*)((char*)Als + tid * 16 + 4096) = sa1;
        *(short8v*)((char*)Bls + tid * 16) = sb0;
        *(short8v*)((char*)Bls + tid * 16 + 4096) = sb1;
        __syncthreads();
        if (s + 1 < NS) stage((s + 1) * 32);

        bf16x8 bfr[4];
#pragma unroll
        for (int nt = 0; nt < 4; ++nt)
            bfr[nt] = ld8((char*)Bls + ((w & 1) * 4 + nt) * 1024 + lane * 16);
#pragma unroll
        for (int mt = 0; mt < 4; ++mt) {
            const bf16x8 af = ld8((char*)Als + ((w >> 1) * 4 + mt) * 1024 + lane * 16);
#pragma unroll
            for (int nt = 0; nt < 4; ++nt)
                acc[mt][nt] = mfma_bf16(af, bfr[nt], acc[mt][nt]);
        }
    }

    // C layout: m = mbase + mt*16 (+r contiguous), n = nbase + nt*16
    const int mbase = m0 + (w >> 1) * 64 + 4 * lg;
    const int nbase = n0 + (w & 1) * 64 + l16;

    if constexpr (MODE == 0) {
        const int kind = j % 3, which = j / 3;
        const float* Bp = g.bias[j];
        if (kind < 2) {
            u16* T = (kind == 0) ? g.outQ[which] : g.outK[which];
            const float s = (kind == 0) ? QSCALE : 1.0f;
#pragma unroll
            for (int mt = 0; mt < 4; ++mt) {
                const int m = mbase + mt * 16;
                const float4 bv = *(const float4*)(Bp + m);
#pragma unroll
                for (int nt = 0; nt < 4; ++nt) {
                    const int l = nbase + nt * 16;
                    const f32x4 a = acc[mt][nt];
                    ushort4 pk;
                    pk.x = bfbits((a.x + bv.x) * s);
                    pk.y = bfbits((a.y + bv.y) * s);
                    pk.z = bfbits((a.z + bv.z) * s);
                    pk.w = bfbits((a.w + bv.w) * s);
                    *(ushort4*)(T + ((long long)(z * 8 + (m >> 6)) * HW_N + l) * 64 + (m & 63)) = pk;
                }
            }
        } else {
            u16* V = g.outV[which];
#pragma unroll
            for (int mt = 0; mt < 4; ++mt) {
                const int m = mbase + mt * 16;
                const float4 bv = *(const float4*)(Bp + m);
#pragma unroll
                for (int nt = 0; nt < 4; ++nt) {
                    const int l = nbase + nt * 16;
                    const f32x4 a = acc[mt][nt];
                    V[((long long)z * 512 + m + 0) * HW_N + l] = bfbits(a.x + bv.x);
                    V[((long long)z * 512 + m + 1) * HW_N + l] = bfbits(a.y + bv.y);
                    V[((long long)z * 512 + m + 2) * HW_N + l] = bfbits(a.z + bv.z);
                    V[((long long)z * 512 + m + 3) * HW_N + l] = bfbits(a.w + bv.w);
                }
            }
        }
    } else if constexpr (MODE == 1) {
        const float* Bp = g.bias[j];
        const u16* Rb = g.R[j];
        float* Ob = g.outT[j];
#pragma unroll
        for (int mt = 0; mt < 4; ++mt) {
            const int m = mbase + mt * 16;
            const float4 bv = *(const float4*)(Bp + m);
#pragma unroll
            for (int nt = 0; nt < 4; ++nt) {
                const int l = nbase + nt * 16;
                const long long rowoff = ((long long)z * HW_N + l) * 256 + m;
                const ushort4 rv = *(const ushort4*)(Rb + rowoff);
                const f32x4 a = acc[mt][nt];
                float4 o;
                o.x = a.x + bv.x + b2f(rv.x);
                o.y = a.y + bv.y + b2f(rv.y);
                o.z = a.z + bv.z + b2f(rv.z);
                o.w = a.w + bv.w + b2f(rv.w);
                *(float4*)(Ob + rowoff) = o;
            }
        }
    } else {
        const float* Bp = g.bias[0];
#pragma unroll
        for (int mt = 0; mt < 4; ++mt) {
            const int m = mbase + mt * 16;
            const float4 bv = *(const float4*)(Bp + m);
            const float4 mu = *(const float4*)(g.bnm + m);
            const float4 vr = *(const float4*)(g.bnv + m);
            const float4 ga = *(const float4*)(g.bng + m);
            const float4 be = *(const float4*)(g.bnb + m);
            const float sc0 = ga.x * rsqrtf(vr.x + EPS_F), sh0 = be.x - mu.x * sc0;
            const float sc1 = ga.y * rsqrtf(vr.y + EPS_F), sh1 = be.y - mu.y * sc1;
            const float sc2 = ga.z * rsqrtf(vr.z + EPS_F), sh2 = be.z - mu.z * sc2;
            const float sc3 = ga.w * rsqrtf(vr.w + EPS_F), sh3 = be.w - mu.w * sc3;
#pragma unroll
            for (int nt = 0; nt < 4; ++nt) {
                const int l = nbase + nt * 16;
                const f32x4 a = acc[mt][nt];
                float* O = g.outC + (long long)z * 256 * HW_N + l;
                O[(long long)(m + 0) * HW_N] = fmaxf((a.x + bv.x) * sc0 + sh0, 0.f);
                O[(long long)(m + 1) * HW_N] = fmaxf((a.y + bv.y) * sc1 + sh1, 0.f);
                O[(long long)(m + 2) * HW_N] = fmaxf((a.z + bv.z) * sc2 + sh2, 0.f);
                O[(long long)(m + 3) * HW_N] = fmaxf((a.w + bv.w) * sc3 + sh3, 0.f);
            }
        }
    }
}

// ---------------------------------------------------------------------------
// MFMA flash cross-attention (same core as round 1); output now bf16 O^T
// [bh][l][64] so the cross GEMM's B-operand is k-contiguous.
// ---------------------------------------------------------------------------
__global__ __launch_bounds__(256)
void attn_mfma_kernel(const u16* __restrict__ qt0, const u16* __restrict__ kt0,
                      const u16* __restrict__ v0b,
                      const u16* __restrict__ qt1, const u16* __restrict__ kt1,
                      const u16* __restrict__ v1b,
                      u16* __restrict__ oat0T, u16* __restrict__ oat1T)
{
    const int flat = blockIdx.x;
    const int virt = (flat & 7) * 144 + (flat >> 3);
    const int lt = virt % 36;
    const int h = (virt / 36) & 7;
    const int zz = virt / 288;
    const int b = zz >> 1, dir = zz & 1;

    const u16* QT = dir ? qt1 : qt0;
    const u16* KT = dir ? kt0 : kt1;
    const u16* V  = dir ? v0b : v1b;

    const long long bh = (long long)(b * 8 + h);
    const u16* Qb = QT + bh * HW_N * 64;
    const u16* Kb = KT + bh * HW_N * 64;
    const u16* Vb = V + ((long long)b * 512 + h * 64) * HW_N;

    const int tid = threadIdx.x;
    const int w = tid >> 6, lane = tid & 63;
    const int l16 = lane & 15, lg = lane >> 4;
    const int l0 = lt * 64;

    __shared__ u16 Ks[64 * 64];
    __shared__ u16 Vs[64 * 64];
    __shared__ u16 Ps[4][16 * 72];

    bf16x8 qf0, qf1;
    {
        const u16* qrow = Qb + (long long)(l0 + 16 * w + l16) * 64 + 8 * lg;
        qf0 = ld8(qrow);
        qf1 = ld8(qrow + 32);
    }

    f32x4 acc0 = {0.f, 0.f, 0.f, 0.f}, acc1 = acc0, acc2 = acc0, acc3 = acc0;
    float m_run = -1e30f, s_run = 0.f;

    const int rsub = lane >> 3;
    const int csub = (lane & 7) * 8;
    const int r0 = 16 * w + rsub, r1 = r0 + 8;
    const int swz0 = (csub * 2) ^ ((r0 & 7) << 4);
    const int swz1 = (csub * 2) ^ ((r1 & 7) << 4);
    const int cb0 = (16 * lg) ^ ((l16 & 7) << 4);
    const int cb1 = (16 * lg + 64) ^ ((l16 & 7) << 4);

    short8v ka, kb2, va, vb2;
    {
        const u16* kbase = Kb + (long long)(16 * w) * 64;
        ka  = *(const short8v*)(kbase + (long long)rsub * 64 + csub);
        kb2 = *(const short8v*)(kbase + (long long)(8 + rsub) * 64 + csub);
        const u16* vbase = Vb + (long long)(16 * w + rsub) * HW_N + csub;
        va  = *(const short8v*)(vbase);
        vb2 = *(const short8v*)(vbase + 8LL * HW_N);
    }

    char* prow = (char*)&Ps[w][0] + 144 * l16;

    for (int t = 0; t < 36; ++t) {
        if (t) __syncthreads();
        *(short8v*)((char*)Ks + r0 * 128 + swz0) = ka;
        *(short8v*)((char*)Ks + r1 * 128 + swz1) = kb2;
        *(short8v*)((char*)Vs + r0 * 128 + swz0) = va;
        *(short8v*)((char*)Vs + r1 * 128 + swz1) = vb2;
        __syncthreads();
        if (t + 1 < 36) {
            const int m0 = (t + 1) * 64;
            const u16* kbase = Kb + (long long)(m0 + 16 * w) * 64;
            ka  = *(const short8v*)(kbase + (long long)rsub * 64 + csub);
            kb2 = *(const short8v*)(kbase + (long long)(8 + rsub) * 64 + csub);
            const u16* vbase = Vb + (long long)(16 * w + rsub) * HW_N + m0 + csub;
            va  = *(const short8v*)(vbase);
            vb2 = *(const short8v*)(vbase + 8LL * HW_N);
        }

        const char* kb_ = (const char*)Ks + l16 * 128;
        f32x4 st0 = {0.f,0.f,0.f,0.f}, st1 = st0, st2 = st0, st3 = st0;
        st0 = mfma_bf16(ld8(kb_ + 0 * 2048 + cb0), qf0, st0);
        st0 = mfma_bf16(ld8(kb_ + 0 * 2048 + cb1), qf1, st0);
        st1 = mfma_bf16(ld8(kb_ + 1 * 2048 + cb0), qf0, st1);
        st1 = mfma_bf16(ld8(kb_ + 1 * 2048 + cb1), qf1, st1);
        st2 = mfma_bf16(ld8(kb_ + 2 * 2048 + cb0), qf0, st2);
        st2 = mfma_bf16(ld8(kb_ + 2 * 2048 + cb1), qf1, st2);
        st3 = mfma_bf16(ld8(kb_ + 3 * 2048 + cb0), qf0, st3);
        st3 = mfma_bf16(ld8(kb_ + 3 * 2048 + cb1), qf1, st3);

        float mx = fmaxf(fmaxf(max4(st0), max4(st1)), fmaxf(max4(st2), max4(st3)));
        mx = fmaxf(mx, __shfl_xor(mx, 16, 64));
        mx = fmaxf(mx, __shfl_xor(mx, 32, 64));
        const float m_new = fmaxf(m_run, mx);
        const float alpha = exp2f(m_run - m_new);

        f32x4 p0, p1, p2, p3;
        p0.x = exp2f(st0.x - m_new); p0.y = exp2f(st0.y - m_new);
        p0.z = exp2f(st0.z - m_new); p0.w = exp2f(st0.w - m_new);
        p1.x = exp2f(st1.x - m_new); p1.y = exp2f(st1.y - m_new);
        p1.z = exp2f(st1.z - m_new); p1.w = exp2f(st1.w - m_new);
        p2.x = exp2f(st2.x - m_new); p2.y = exp2f(st2.y - m_new);
        p2.z = exp2f(st2.z - m_new); p2.w = exp2f(st2.w - m_new);
        p3.x = exp2f(st3.x - m_new); p3.y = exp2f(st3.y - m_new);
        p3.z = exp2f(st3.z - m_new); p3.w = exp2f(st3.w - m_new);

        float psum = sum4(p0) + sum4(p1) + sum4(p2) + sum4(p3);
        psum += __shfl_xor(psum, 16, 64);
        psum += __shfl_xor(psum, 32, 64);
        s_run = s_run * alpha + psum;
        m_run = m_new;
        acc0 *= alpha; acc1 *= alpha; acc2 *= alpha; acc3 *= alpha;

        *(unsigned*)(prow + 8 * lg + 0)   = pack2(p0.x, p0.y);
        *(unsigned*)(prow + 8 * lg + 4)   = pack2(p0.z, p0.w);
        *(unsigned*)(prow + 8 * lg + 32)  = pack2(p1.x, p1.y);
        *(unsigned*)(prow + 8 * lg + 36)  = pack2(p1.z, p1.w);
        *(unsigned*)(prow + 8 * lg + 64)  = pack2(p2.x, p2.y);
        *(unsigned*)(prow + 8 * lg + 68)  = pack2(p2.z, p2.w);
        *(unsigned*)(prow + 8 * lg + 96)  = pack2(p3.x, p3.y);
        *(unsigned*)(prow + 8 * lg + 100) = pack2(p3.z, p3.w);

        bf16x8 pf0 = ld8(prow + 16 * lg);
        bf16x8 pf1 = ld8(prow + 64 + 16 * lg);
        const char* vb_ = (const char*)Vs + l16 * 128;
        acc0 = mfma_bf16(ld8(vb_ + 0 * 2048 + cb0), pf0, acc0);
        acc0 = mfma_bf16(ld8(vb_ + 0 * 2048 + cb1), pf1, acc0);
        acc1 = mfma_bf16(ld8(vb_ + 1 * 2048 + cb0), pf0, acc1);
        acc1 = mfma_bf16(ld8(vb_ + 1 * 2048 + cb1), pf1, acc1);
        acc2 = mfma_bf16(ld8(vb_ + 2 * 2048 + cb0), pf0, acc2);
        acc2 = mfma_bf16(ld8(vb_ + 2 * 2048 + cb1), pf1, acc2);
        acc3 = mfma_bf16(ld8(vb_ + 3 * 2048 + cb0), pf0, acc3);
        acc3 = mfma_bf16(ld8(vb_ + 3 * 2048 + cb1), pf1, acc3);
    }

    const float inv = 1.0f / s_run;
    u16* obase = (dir ? oat1T : oat0T) +
                 ((long long)(b * 8 + h) * HW_N + l0 + 16 * w + l16) * 64;
#define OSTORE(T4, A) { \
    ushort4 pk; \
    pk.x = bfbits(A.x * inv); pk.y = bfbits(A.y * inv); \
    pk.z = bfbits(A.z * inv); pk.w = bfbits(A.w * inv); \
    *(ushort4*)(obase + (T4) * 16 + 4 * lg) = pk; }
    OSTORE(0, acc0) OSTORE(1, acc1) OSTORE(2, acc2) OSTORE(3, acc3)
#undef OSTORE
}

// ---------------------------------------------------------------------------
// Channel LayerNorm on transposed layout: mpreT fp32 [b][l][256] -> bf16
// grid (36, 2b, 2dir); 4 lanes per row.
// ---------------------------------------------------------------------------
__global__ __launch_bounds__(256)
void ln_t_kernel(const float* __restrict__ mpre0T, const float* __restrict__ mpre1T,
                 const float* __restrict__ g1, const float* __restrict__ b1,
                 const float* __restrict__ g2, const float* __restrict__ b2,
                 u16* __restrict__ mln0T, u16* __restrict__ mln1T)
{
    const int l = blockIdx.x * 64 + (threadIdx.x >> 2);
    const int z = blockIdx.y, dir = blockIdx.z;
    const float* src = (dir ? mpre1T : mpre0T) + ((long long)z * HW_N + l) * 256;
    const float* gg = dir ? g2 : g1;
    const float* bb = dir ? b2 : b1;
    u16* dst = (dir ? mln1T : mln0T) + ((long long)z * HW_N + l) * 256;
    const int q = (threadIdx.x & 3) * 64;

    float4 vbuf[16];
    float sum = 0.f, sq = 0.f;
#pragma unroll
    for (int i = 0; i < 16; ++i) {
        const float4 v = *(const float4*)(src + q + i * 4);
        vbuf[i] = v;
        sum += (v.x + v.y) + (v.z + v.w);
        sq += (v.x * v.x + v.y * v.y) + (v.z * v.z + v.w * v.w);
    }
    sum += __shfl_xor(sum, 1, 64); sum += __shfl_xor(sum, 2, 64);
    sq  += __shfl_xor(sq, 1, 64);  sq  += __shfl_xor(sq, 2, 64);
    const float mean = sum * (1.f / 256.f);
    const float var = sq * (1.f / 256.f) - mean * mean;
    const float rstd = rsqrtf(var + EPS_F);
#pragma unroll
    for (int i = 0; i < 16; ++i) {
        const int c = q + i * 4;
        const float4 gv = *(const float4*)(gg + c);
        const float4 bv = *(const float4*)(bb + c);
        ushort4 pk;
        pk.x = bfbits((vbuf[i].x - mean) * rstd * gv.x + bv.x);
        pk.y = bfbits((vbuf[i].y - mean) * rstd * gv.y + bv.y);
        pk.z = bfbits((vbuf[i].z - mean) * rstd * gv.z + bv.z);
        pk.w = bfbits((vbuf[i].w - mean) * rstd * gv.w + bv.w);
        *(ushort4*)(dst + c) = pk;
    }
}

// ---------------------------------------------------------------------------
extern "C" void kernel_launch(void* const* d_in, const int* in_sizes, int n_in,
                              void* d_out, int out_size, void* d_ws, size_t ws_size,
                              hipStream_t stream)
{
    (void)in_sizes; (void)n_in; (void)out_size; (void)ws_size;

    const float* modal1 = (const float*)d_in[0];
    const float* modal2 = (const float*)d_in[1];
    const float* wqkv[6]; const float* bqkv[6];
    for (int j = 0; j < 6; ++j) {
        wqkv[j] = (const float*)d_in[2 + 2 * j];
        bqkv[j] = (const float*)d_in[3 + 2 * j];
    }
    const float* wo1 = (const float*)d_in[14];
    const float* bo1 = (const float*)d_in[15];
    const float* wo2 = (const float*)d_in[16];
    const float* bo2 = (const float*)d_in[17];
    const float* ln1_g = (const float*)d_in[18];
    const float* ln1_b = (const float*)d_in[19];
    const float* ln2_g = (const float*)d_in[20];
    const float* ln2_b = (const float*)d_in[21];
    const float* wf = (const float*)d_in[22];
    const float* bf = (const float*)d_in[23];
    const float* bn_g = (const float*)d_in[24];
    const float* bn_b = (const float*)d_in[25];
    const float* bn_mean = (const float*)d_in[26];
    const float* bn_var = (const float*)d_in[27];

    char* ws = (char*)d_ws;
    size_t off = 0;
    auto alloc = [&](size_t bytes) { char* p = ws + off; off += (bytes + 255) & ~(size_t)255; return p; };

    u16* modalT[2]; u16* wbf[9]; u16* qT[2]; u16* kT[2]; u16* vC[2];
    u16* oatT[2]; float* mpreT[2]; u16* mlnT[2];
    for (int i = 0; i < 2; ++i) modalT[i] = (u16*)alloc(2LL * HW_N * 256 * 2);
    for (int i = 0; i < 9; ++i) wbf[i] = (u16*)alloc(131072 * 2);
    for (int i = 0; i < 2; ++i) qT[i] = (u16*)alloc(2LL * 512 * HW_N * 2);
    for (int i = 0; i < 2; ++i) kT[i] = (u16*)alloc(2LL * 512 * HW_N * 2);
    for (int i = 0; i < 2; ++i) vC[i] = (u16*)alloc(2LL * 512 * HW_N * 2);
    for (int i = 0; i < 2; ++i) oatT[i] = (u16*)alloc(2LL * 512 * HW_N * 2);
    for (int i = 0; i < 2; ++i) mpreT[i] = (float*)alloc(2LL * HW_N * 256 * 4);
    for (int i = 0; i < 2; ++i) mlnT[i] = (u16*)alloc(2LL * HW_N * 256 * 2);

    // --- prep: weights -> bf16; modal feats -> transposed bf16
    WPtrs wp;
    for (int j = 0; j < 6; ++j) { wp.s[j] = wqkv[j]; wp.d[j] = wbf[j]; }
    wp.s[6] = wo1; wp.d[6] = wbf[6];
    wp.s[7] = wo2; wp.d[7] = wbf[7];
    wp.s[8] = wf;  wp.d[8] = wbf[8];
    conv_w_kernel<<<dim3(128, 1, 9), 256, 0, stream>>>(wp);
    prep_modal_kernel<<<dim3(36, 4, 4), 256, 0, stream>>>(modal1, modal2, modalT[0], modalT[1]);

    // --- QKV projections (MFMA)
    GArgs g0 = {};
    for (int j = 0; j < 6; ++j) { g0.W[j] = wbf[j]; g0.bias[j] = bqkv[j]; }
    g0.X[0] = modalT[0]; g0.X[1] = modalT[1];
    for (int i = 0; i < 2; ++i) { g0.outQ[i] = qT[i]; g0.outK[i] = kT[i]; g0.outV[i] = vC[i]; }
    gemm_mfma<0><<<dim3(72, 2, 6), 256, 0, stream>>>(g0);

    // --- flash cross-attention (MFMA) -> bf16 O^T
    attn_mfma_kernel<<<dim3(36 * 8 * 4), 256, 0, stream>>>(
        qT[0], kT[0], vC[0], qT[1], kT[1], vC[1], oatT[0], oatT[1]);

    // --- output projection + residual -> fp32 transposed
    GArgs g1a = {};
    g1a.W[0] = wbf[6]; g1a.W[1] = wbf[7];
    g1a.bias[0] = bo1; g1a.bias[1] = bo2;
    g1a.X[0] = oatT[0]; g1a.X[1] = oatT[1];
    g1a.R[0] = modalT[0]; g1a.R[1] = modalT[1];
    g1a.outT[0] = mpreT[0]; g1a.outT[1] = mpreT[1];
    gemm_mfma<1><<<dim3(36, 2, 2), 256, 0, stream>>>(g1a);

    // --- channel LayerNorm -> bf16 transposed
    ln_t_kernel<<<dim3(36, 2, 2), 256, 0, stream>>>(
        mpreT[0], mpreT[1], ln1_g, ln1_b, ln2_g, ln2_b, mlnT[0], mlnT[1]);

    // --- fusion conv + BN + ReLU -> d_out (fp32 conv layout)
    GArgs g2a = {};
    g2a.W[0] = wbf[8]; g2a.bias[0] = bf;
    g2a.X[0] = mlnT[0]; g2a.X[1] = mlnT[1];
    g2a.outC = (float*)d_out;
    g2a.bnm = bn_mean; g2a.bnv = bn_var; g2a.bng = bn_g; g2a.bnb = bn_b;
    gemm_mfma<2><<<dim3(36, 2, 1), 256, 0, stream>>>(g2a);
}

// Round 4
// 173.819 us; speedup vs baseline: 6.6663x; 1.1221x over previous
//
#include <hip/hip_runtime.h>
#include <hip/hip_bf16.h>

#define HW_N 2304
#define EPS_F 1e-5f
#define QSCALE 0.18033688011112043f   // 0.125 * log2(e)

typedef float f32x4 __attribute__((ext_vector_type(4)));
typedef short short8v __attribute__((ext_vector_type(8)));
typedef __bf16 bf16x8 __attribute__((ext_vector_type(8)));
typedef unsigned short u16;

__device__ __forceinline__ f32x4 mfma_bf16(bf16x8 a, bf16x8 b, f32x4 c) {
    return __builtin_amdgcn_mfma_f32_16x16x32_bf16(a, b, c, 0, 0, 0);
}
__device__ __forceinline__ bf16x8 ld8(const void* p) {
    return __builtin_bit_cast(bf16x8, *(const short8v*)p);
}
__device__ __forceinline__ unsigned short bfbits(float v) {
    return __builtin_bit_cast(unsigned short, __float2bfloat16(v));
}
__device__ __forceinline__ float b2f(u16 u) {
    unsigned x = (unsigned)u << 16;
    return __builtin_bit_cast(float, x);
}
__device__ __forceinline__ unsigned pack2(float lo, float hi) {
    return (unsigned)bfbits(lo) | ((unsigned)bfbits(hi) << 16);
}
__device__ __forceinline__ float max4(f32x4 v) {
    return fmaxf(fmaxf(v.x, v.y), fmaxf(v.z, v.w));
}

// ---------------------------------------------------------------------------
// Prep: convert 9 weight matrices (all 131072 elements) fp32 -> bf16
// ---------------------------------------------------------------------------
struct WPtrs { const float* s[9]; u16* d[9]; };

__global__ __launch_bounds__(256)
void conv_w_kernel(WPtrs p)
{
    const int j = blockIdx.z;
    const float* s = p.s[j];
    u16* d = p.d[j];
    const int i = (blockIdx.x * 256 + threadIdx.x) * 4;
    const float4 v = *(const float4*)(s + i);
    ushort4 pk;
    pk.x = bfbits(v.x); pk.y = bfbits(v.y); pk.z = bfbits(v.z); pk.w = bfbits(v.w);
    *(ushort4*)(d + i) = pk;
}

// ---------------------------------------------------------------------------
// Prep: transpose modal feats [b][256][2304] fp32 -> [b][2304][256] bf16
// ---------------------------------------------------------------------------
__global__ __launch_bounds__(256)
void prep_modal_kernel(const float* __restrict__ m1, const float* __restrict__ m2,
                       u16* __restrict__ t1, u16* __restrict__ t2)
{
    const int l0 = blockIdx.x * 64, c0 = blockIdx.y * 64;
    const int which = blockIdx.z >> 1, b = blockIdx.z & 1;
    const float* src = (which ? m2 : m1) + ((long long)b * 256 + c0) * HW_N + l0;
    u16* dst = (which ? t2 : t1) + ((long long)b * HW_N + l0) * 256 + c0;

    __shared__ float tile[64][65];
    const int t = threadIdx.x;
    const int r = t >> 4, cq = (t & 15) * 4;
#pragma unroll
    for (int i = 0; i < 4; ++i) {
        const int row = r + i * 16;
        const float4 v = *(const float4*)(src + (long long)row * HW_N + cq);
        tile[row][cq + 0] = v.x; tile[row][cq + 1] = v.y;
        tile[row][cq + 2] = v.z; tile[row][cq + 3] = v.w;
    }
    __syncthreads();
#pragma unroll
    for (int i = 0; i < 4; ++i) {
        const int lr = r + i * 16;
        ushort4 pk;
        pk.x = bfbits(tile[cq + 0][lr]);
        pk.y = bfbits(tile[cq + 1][lr]);
        pk.z = bfbits(tile[cq + 2][lr]);
        pk.w = bfbits(tile[cq + 3][lr]);
        *(ushort4*)(dst + (long long)lr * 256 + cq) = pk;
    }
}

// ---------------------------------------------------------------------------
// Generic MFMA GEMM (unchanged from round 3)
// ---------------------------------------------------------------------------
struct GArgs {
    const u16* W[6];
    const float* bias[6];
    const u16* X[2];
    const u16* R[2];
    u16* outQ[2]; u16* outK[2]; u16* outV[2];
    float* outT[2];
    float* outC;
    const float *bnm, *bnv, *bng, *bnb;
};

template<int MODE>
__global__ __launch_bounds__(256)
void gemm_mfma(GArgs g)
{
    constexpr int KD = (MODE == 0) ? 256 : 512;
    constexpr int NS = KD / 32;
    const int z = blockIdx.y;
    const int j = blockIdx.z;
    const int mt_b = blockIdx.x / 18;
    const int nt_b = blockIdx.x - mt_b * 18;
    const int m0 = mt_b * 128, n0 = nt_b * 128;

    const u16* Wb = g.W[(MODE == 2) ? 0 : j];
    const u16* Xb0 = (MODE == 0) ? g.X[(j < 3) ? 0 : 1]
                                 : ((MODE == 1) ? g.X[j] : nullptr);

    __shared__ u16 Als[4096];
    __shared__ u16 Bls[4096];

    const int tid = threadIdx.x;
    const int w = tid >> 6, lane = tid & 63;
    const int l16 = lane & 15, lg = lane >> 4;

    const int ar0 = (((tid >> 6) << 4) | (tid & 15));
    const int k8 = (tid >> 4) & 3;

    short8v sa0, sa1, sb0, sb1;

    auto stage = [&](int kb) {
        const int koff = kb + k8 * 8;
        sa0 = *(const short8v*)(Wb + (long long)(m0 + ar0) * KD + koff);
        sa1 = *(const short8v*)(Wb + (long long)(m0 + ar0 + 64) * KD + koff);
        if constexpr (MODE == 0) {
            const u16* p = Xb0 + ((long long)z * HW_N + n0 + ar0) * 256 + koff;
            sb0 = *(const short8v*)p;
            sb1 = *(const short8v*)(p + 64LL * 256);
        } else if constexpr (MODE == 1) {
            const int head = kb >> 6;
            const u16* p = Xb0 + (((long long)z * 8 + head) * HW_N + n0 + ar0) * 64 + (koff & 63);
            sb0 = *(const short8v*)p;
            sb1 = *(const short8v*)(p + 64LL * 64);
        } else {
            const u16* Xb = (kb < 256) ? g.X[0] : g.X[1];
            const u16* p = Xb + ((long long)z * HW_N + n0 + ar0) * 256 + (koff & 255);
            sb0 = *(const short8v*)p;
            sb1 = *(const short8v*)(p + 64LL * 256);
        }
    };

    f32x4 acc[4][4];
#pragma unroll
    for (int a = 0; a < 4; ++a)
#pragma unroll
        for (int b = 0; b < 4; ++b) acc[a][b] = f32x4{0.f, 0.f, 0.f, 0.f};

    stage(0);
    for (int s = 0; s < NS; ++s) {
        __syncthreads();
        *(short8v*)((char*)Als + tid * 16) = sa0;
        *(short8v*)((char*)Als + tid * 16 + 4096) = sa1;
        *(short8v*)((char*)Bls + tid * 16) = sb0;
        *(short8v*)((char*)Bls + tid * 16 + 4096) = sb1;
        __syncthreads();
        if (s + 1 < NS) stage((s + 1) * 32);

        bf16x8 bfr[4];
#pragma unroll
        for (int nt = 0; nt < 4; ++nt)
            bfr[nt] = ld8((char*)Bls + ((w & 1) * 4 + nt) * 1024 + lane * 16);
#pragma unroll
        for (int mt = 0; mt < 4; ++mt) {
            const bf16x8 af = ld8((char*)Als + ((w >> 1) * 4 + mt) * 1024 + lane * 16);
#pragma unroll
            for (int nt = 0; nt < 4; ++nt)
                acc[mt][nt] = mfma_bf16(af, bfr[nt], acc[mt][nt]);
        }
    }

    const int mbase = m0 + (w >> 1) * 64 + 4 * lg;
    const int nbase = n0 + (w & 1) * 64 + l16;

    if constexpr (MODE == 0) {
        const int kind = j % 3, which = j / 3;
        const float* Bp = g.bias[j];
        if (kind < 2) {
            u16* T = (kind == 0) ? g.outQ[which] : g.outK[which];
            const float s = (kind == 0) ? QSCALE : 1.0f;
#pragma unroll
            for (int mt = 0; mt < 4; ++mt) {
                const int m = mbase + mt * 16;
                const float4 bv = *(const float4*)(Bp + m);
#pragma unroll
                for (int nt = 0; nt < 4; ++nt) {
                    const int l = nbase + nt * 16;
                    const f32x4 a = acc[mt][nt];
                    ushort4 pk;
                    pk.x = bfbits((a.x + bv.x) * s);
                    pk.y = bfbits((a.y + bv.y) * s);
                    pk.z = bfbits((a.z + bv.z) * s);
                    pk.w = bfbits((a.w + bv.w) * s);
                    *(ushort4*)(T + ((long long)(z * 8 + (m >> 6)) * HW_N + l) * 64 + (m & 63)) = pk;
                }
            }
        } else {
            u16* V = g.outV[which];
#pragma unroll
            for (int mt = 0; mt < 4; ++mt) {
                const int m = mbase + mt * 16;
                const float4 bv = *(const float4*)(Bp + m);
#pragma unroll
                for (int nt = 0; nt < 4; ++nt) {
                    const int l = nbase + nt * 16;
                    const f32x4 a = acc[mt][nt];
                    V[((long long)z * 512 + m + 0) * HW_N + l] = bfbits(a.x + bv.x);
                    V[((long long)z * 512 + m + 1) * HW_N + l] = bfbits(a.y + bv.y);
                    V[((long long)z * 512 + m + 2) * HW_N + l] = bfbits(a.z + bv.z);
                    V[((long long)z * 512 + m + 3) * HW_N + l] = bfbits(a.w + bv.w);
                }
            }
        }
    } else if constexpr (MODE == 1) {
        const float* Bp = g.bias[j];
        const u16* Rb = g.R[j];
        float* Ob = g.outT[j];
#pragma unroll
        for (int mt = 0; mt < 4; ++mt) {
            const int m = mbase + mt * 16;
            const float4 bv = *(const float4*)(Bp + m);
#pragma unroll
            for (int nt = 0; nt < 4; ++nt) {
                const int l = nbase + nt * 16;
                const long long rowoff = ((long long)z * HW_N + l) * 256 + m;
                const ushort4 rv = *(const ushort4*)(Rb + rowoff);
                const f32x4 a = acc[mt][nt];
                float4 o;
                o.x = a.x + bv.x + b2f(rv.x);
                o.y = a.y + bv.y + b2f(rv.y);
                o.z = a.z + bv.z + b2f(rv.z);
                o.w = a.w + bv.w + b2f(rv.w);
                *(float4*)(Ob + rowoff) = o;
            }
        }
    } else {
        const float* Bp = g.bias[0];
#pragma unroll
        for (int mt = 0; mt < 4; ++mt) {
            const int m = mbase + mt * 16;
            const float4 bv = *(const float4*)(Bp + m);
            const float4 mu = *(const float4*)(g.bnm + m);
            const float4 vr = *(const float4*)(g.bnv + m);
            const float4 ga = *(const float4*)(g.bng + m);
            const float4 be = *(const float4*)(g.bnb + m);
            const float sc0 = ga.x * rsqrtf(vr.x + EPS_F), sh0 = be.x - mu.x * sc0;
            const float sc1 = ga.y * rsqrtf(vr.y + EPS_F), sh1 = be.y - mu.y * sc1;
            const float sc2 = ga.z * rsqrtf(vr.z + EPS_F), sh2 = be.z - mu.z * sc2;
            const float sc3 = ga.w * rsqrtf(vr.w + EPS_F), sh3 = be.w - mu.w * sc3;
#pragma unroll
            for (int nt = 0; nt < 4; ++nt) {
                const int l = nbase + nt * 16;
                const f32x4 a = acc[mt][nt];
                float* O = g.outC + (long long)z * 256 * HW_N + l;
                O[(long long)(m + 0) * HW_N] = fmaxf((a.x + bv.x) * sc0 + sh0, 0.f);
                O[(long long)(m + 1) * HW_N] = fmaxf((a.y + bv.y) * sc1 + sh1, 0.f);
                O[(long long)(m + 2) * HW_N] = fmaxf((a.z + bv.z) * sc2 + sh2, 0.f);
                O[(long long)(m + 3) * HW_N] = fmaxf((a.w + bv.w) * sc3 + sh3, 0.f);
            }
        }
    }
}

// ---------------------------------------------------------------------------
// MFMA flash cross-attention, v2:
//   - double-buffered K/V LDS, ONE barrier per kv-tile
//   - conflict-free XOR-swizzled per-wave P buffer (b64 writes / b128 reads)
//   - psum via all-ones MFMA (no shuffle reductions for the denominator)
//   - defer-max rescale (THR=8 in log2 domain), s_setprio around MFMA
// ---------------------------------------------------------------------------
__global__ __launch_bounds__(256)
void attn_mfma_kernel(const u16* __restrict__ qt0, const u16* __restrict__ kt0,
                      const u16* __restrict__ v0b,
                      const u16* __restrict__ qt1, const u16* __restrict__ kt1,
                      const u16* __restrict__ v1b,
                      u16* __restrict__ oat0T, u16* __restrict__ oat1T)
{
    const int flat = blockIdx.x;
    const int virt = (flat & 7) * 144 + (flat >> 3);
    const int lt = virt % 36;
    const int h = (virt / 36) & 7;
    const int zz = virt / 288;
    const int b = zz >> 1, dir = zz & 1;

    const u16* QT = dir ? qt1 : qt0;
    const u16* KT = dir ? kt0 : kt1;
    const u16* V  = dir ? v0b : v1b;

    const long long bh = (long long)(b * 8 + h);
    const u16* Qb = QT + bh * HW_N * 64;
    const u16* Kb = KT + bh * HW_N * 64;
    const u16* Vb = V + ((long long)b * 512 + h * 64) * HW_N;

    const int tid = threadIdx.x;
    const int w = tid >> 6, lane = tid & 63;
    const int l16 = lane & 15, lg = lane >> 4;
    const int l0 = lt * 64;

    __shared__ u16 Ks[2][64 * 64];
    __shared__ u16 Vs[2][64 * 64];
    __shared__ u16 Ps[4][16 * 64];   // per-wave, XOR-swizzled [l16][m]

    bf16x8 qf0, qf1;
    {
        const u16* qrow = Qb + (long long)(l0 + 16 * w + l16) * 64 + 8 * lg;
        qf0 = ld8(qrow);
        qf1 = ld8(qrow + 32);
    }
    bf16x8 onesv;
    {
        short8v o;
#pragma unroll
        for (int i = 0; i < 8; ++i) o[i] = (short)0x3F80;
        onesv = __builtin_bit_cast(bf16x8, o);
    }

    f32x4 acc0 = {0.f, 0.f, 0.f, 0.f}, acc1 = acc0, acc2 = acc0, acc3 = acc0;
    f32x4 accs = acc0;                 // denominator accumulator (all-ones MFMA)
    float m_run = -1e30f;

    const int rsub = lane >> 3;
    const int csub = (lane & 7) * 8;
    const int r0 = 16 * w + rsub, r1 = r0 + 8;
    const int swz0 = (csub * 2) ^ ((r0 & 7) << 4);
    const int swz1 = (csub * 2) ^ ((r1 & 7) << 4);
    const int cb0 = (16 * lg) ^ ((l16 & 7) << 4);
    const int cb1 = (16 * lg + 64) ^ ((l16 & 7) << 4);

    short8v ka, kb2, va, vb2;
    auto stage = [&](int t) {
        const int m0 = t * 64;
        const u16* kbase = Kb + (long long)(m0 + 16 * w) * 64;
        ka  = *(const short8v*)(kbase + (long long)rsub * 64 + csub);
        kb2 = *(const short8v*)(kbase + (long long)(8 + rsub) * 64 + csub);
        const u16* vbase = Vb + (long long)(16 * w + rsub) * HW_N + m0 + csub;
        va  = *(const short8v*)(vbase);
        vb2 = *(const short8v*)(vbase + 8LL * HW_N);
    };
    auto commit = [&](int buf) {
        *(short8v*)((char*)Ks[buf] + r0 * 128 + swz0) = ka;
        *(short8v*)((char*)Ks[buf] + r1 * 128 + swz1) = kb2;
        *(short8v*)((char*)Vs[buf] + r0 * 128 + swz0) = va;
        *(short8v*)((char*)Vs[buf] + r1 * 128 + swz1) = vb2;
    };

    // P-buffer addressing: A(l16,m) = l16*128 + (((m>>3)^(l16&7))<<4) + (m&7)*2
    char* Pw = (char*)&Ps[w][0];
    const int pxor = l16 & 7;
    const int pw_hi = lg >> 1;              // (m>>3) contribution from lg
    const int pw_lo = 8 * (lg & 1);         // byte offset within chunk
    const int prow = l16 * 128;
    const int pr0 = prow + ((lg ^ pxor) << 4);
    const int pr1 = prow + (((4 + lg) ^ pxor) << 4);

    stage(0); commit(0); stage(1);
    __syncthreads();

    for (int t = 0; t < 36; ++t) {
        const int cur = t & 1;
        if (t + 1 < 36) commit(cur ^ 1);
        if (t + 2 < 36) stage(t + 2);

        // ---- QK^T: S^T tiles [16m x 16l]
        const char* kb_ = (const char*)Ks[cur] + l16 * 128;
        f32x4 st0 = {0.f,0.f,0.f,0.f}, st1 = st0, st2 = st0, st3 = st0;
        __builtin_amdgcn_s_setprio(1);
        st0 = mfma_bf16(ld8(kb_ + 0 * 2048 + cb0), qf0, st0);
        st0 = mfma_bf16(ld8(kb_ + 0 * 2048 + cb1), qf1, st0);
        st1 = mfma_bf16(ld8(kb_ + 1 * 2048 + cb0), qf0, st1);
        st1 = mfma_bf16(ld8(kb_ + 1 * 2048 + cb1), qf1, st1);
        st2 = mfma_bf16(ld8(kb_ + 2 * 2048 + cb0), qf0, st2);
        st2 = mfma_bf16(ld8(kb_ + 2 * 2048 + cb1), qf1, st2);
        st3 = mfma_bf16(ld8(kb_ + 3 * 2048 + cb0), qf0, st3);
        st3 = mfma_bf16(ld8(kb_ + 3 * 2048 + cb1), qf1, st3);
        __builtin_amdgcn_s_setprio(0);

        // ---- online softmax with deferred rescale (log2 domain)
        float mx = fmaxf(fmaxf(max4(st0), max4(st1)), fmaxf(max4(st2), max4(st3)));
        mx = fmaxf(mx, __shfl_xor(mx, 16, 64));
        mx = fmaxf(mx, __shfl_xor(mx, 32, 64));
        if (!__all(mx <= m_run + 8.f)) {
            const float m_new = fmaxf(m_run, mx);
            const float alpha = exp2f(m_run - m_new);
            acc0 *= alpha; acc1 *= alpha; acc2 *= alpha; acc3 *= alpha;
            accs *= alpha;
            m_run = m_new;
        }

        f32x4 p0, p1, p2, p3;
        p0.x = exp2f(st0.x - m_run); p0.y = exp2f(st0.y - m_run);
        p0.z = exp2f(st0.z - m_run); p0.w = exp2f(st0.w - m_run);
        p1.x = exp2f(st1.x - m_run); p1.y = exp2f(st1.y - m_run);
        p1.z = exp2f(st1.z - m_run); p1.w = exp2f(st1.w - m_run);
        p2.x = exp2f(st2.x - m_run); p2.y = exp2f(st2.y - m_run);
        p2.z = exp2f(st2.z - m_run); p2.w = exp2f(st2.w - m_run);
        p3.x = exp2f(st3.x - m_run); p3.y = exp2f(st3.y - m_run);
        p3.z = exp2f(st3.z - m_run); p3.w = exp2f(st3.w - m_run);

        // ---- pack P -> per-wave LDS (conflict-free b64 writes)
        {
            uint2 u;
            u.x = pack2(p0.x, p0.y); u.y = pack2(p0.z, p0.w);
            *(uint2*)(Pw + prow + (((0 + pw_hi) ^ pxor) << 4) + pw_lo) = u;
            u.x = pack2(p1.x, p1.y); u.y = pack2(p1.z, p1.w);
            *(uint2*)(Pw + prow + (((2 + pw_hi) ^ pxor) << 4) + pw_lo) = u;
            u.x = pack2(p2.x, p2.y); u.y = pack2(p2.z, p2.w);
            *(uint2*)(Pw + prow + (((4 + pw_hi) ^ pxor) << 4) + pw_lo) = u;
            u.x = pack2(p3.x, p3.y); u.y = pack2(p3.z, p3.w);
            *(uint2*)(Pw + prow + (((6 + pw_hi) ^ pxor) << 4) + pw_lo) = u;
        }

        // ---- PV: O^T tiles [16dv x 16l] + denominator via all-ones MFMA
        bf16x8 pf0 = ld8(Pw + pr0);
        bf16x8 pf1 = ld8(Pw + pr1);
        const char* vb_ = (const char*)Vs[cur] + l16 * 128;
        __builtin_amdgcn_s_setprio(1);
        acc0 = mfma_bf16(ld8(vb_ + 0 * 2048 + cb0), pf0, acc0);
        acc0 = mfma_bf16(ld8(vb_ + 0 * 2048 + cb1), pf1, acc0);
        acc1 = mfma_bf16(ld8(vb_ + 1 * 2048 + cb0), pf0, acc1);
        acc1 = mfma_bf16(ld8(vb_ + 1 * 2048 + cb1), pf1, acc1);
        acc2 = mfma_bf16(ld8(vb_ + 2 * 2048 + cb0), pf0, acc2);
        acc2 = mfma_bf16(ld8(vb_ + 2 * 2048 + cb1), pf1, acc2);
        acc3 = mfma_bf16(ld8(vb_ + 3 * 2048 + cb0), pf0, acc3);
        acc3 = mfma_bf16(ld8(vb_ + 3 * 2048 + cb1), pf1, acc3);
        accs = mfma_bf16(onesv, pf0, accs);
        accs = mfma_bf16(onesv, pf1, accs);
        __builtin_amdgcn_s_setprio(0);

        __syncthreads();
    }

    const float inv = 1.0f / accs.x;   // denominator is lane-local (col = l16)
    u16* obase = (dir ? oat1T : oat0T) +
                 ((long long)(b * 8 + h) * HW_N + l0 + 16 * w + l16) * 64;
#define OSTORE(T4, A) { \
    ushort4 pk; \
    pk.x = bfbits(A.x * inv); pk.y = bfbits(A.y * inv); \
    pk.z = bfbits(A.z * inv); pk.w = bfbits(A.w * inv); \
    *(ushort4*)(obase + (T4) * 16 + 4 * lg) = pk; }
    OSTORE(0, acc0) OSTORE(1, acc1) OSTORE(2, acc2) OSTORE(3, acc3)
#undef OSTORE
}

// ---------------------------------------------------------------------------
// Channel LayerNorm on transposed layout (unchanged)
// ---------------------------------------------------------------------------
__global__ __launch_bounds__(256)
void ln_t_kernel(const float* __restrict__ mpre0T, const float* __restrict__ mpre1T,
                 const float* __restrict__ g1, const float* __restrict__ b1,
                 const float* __restrict__ g2, const float* __restrict__ b2,
                 u16* __restrict__ mln0T, u16* __restrict__ mln1T)
{
    const int l = blockIdx.x * 64 + (threadIdx.x >> 2);
    const int z = blockIdx.y, dir = blockIdx.z;
    const float* src = (dir ? mpre1T : mpre0T) + ((long long)z * HW_N + l) * 256;
    const float* gg = dir ? g2 : g1;
    const float* bb = dir ? b2 : b1;
    u16* dst = (dir ? mln1T : mln0T) + ((long long)z * HW_N + l) * 256;
    const int q = (threadIdx.x & 3) * 64;

    float4 vbuf[16];
    float sum = 0.f, sq = 0.f;
#pragma unroll
    for (int i = 0; i < 16; ++i) {
        const float4 v = *(const float4*)(src + q + i * 4);
        vbuf[i] = v;
        sum += (v.x + v.y) + (v.z + v.w);
        sq += (v.x * v.x + v.y * v.y) + (v.z * v.z + v.w * v.w);
    }
    sum += __shfl_xor(sum, 1, 64); sum += __shfl_xor(sum, 2, 64);
    sq  += __shfl_xor(sq, 1, 64);  sq  += __shfl_xor(sq, 2, 64);
    const float mean = sum * (1.f / 256.f);
    const float var = sq * (1.f / 256.f) - mean * mean;
    const float rstd = rsqrtf(var + EPS_F);
#pragma unroll
    for (int i = 0; i < 16; ++i) {
        const int c = q + i * 4;
        const float4 gv = *(const float4*)(gg + c);
        const float4 bv = *(const float4*)(bb + c);
        ushort4 pk;
        pk.x = bfbits((vbuf[i].x - mean) * rstd * gv.x + bv.x);
        pk.y = bfbits((vbuf[i].y - mean) * rstd * gv.y + bv.y);
        pk.z = bfbits((vbuf[i].z - mean) * rstd * gv.z + bv.z);
        pk.w = bfbits((vbuf[i].w - mean) * rstd * gv.w + bv.w);
        *(ushort4*)(dst + c) = pk;
    }
}

// ---------------------------------------------------------------------------
extern "C" void kernel_launch(void* const* d_in, const int* in_sizes, int n_in,
                              void* d_out, int out_size, void* d_ws, size_t ws_size,
                              hipStream_t stream)
{
    (void)in_sizes; (void)n_in; (void)out_size; (void)ws_size;

    const float* modal1 = (const float*)d_in[0];
    const float* modal2 = (const float*)d_in[1];
    const float* wqkv[6]; const float* bqkv[6];
    for (int j = 0; j < 6; ++j) {
        wqkv[j] = (const float*)d_in[2 + 2 * j];
        bqkv[j] = (const float*)d_in[3 + 2 * j];
    }
    const float* wo1 = (const float*)d_in[14];
    const float* bo1 = (const float*)d_in[15];
    const float* wo2 = (const float*)d_in[16];
    const float* bo2 = (const float*)d_in[17];
    const float* ln1_g = (const float*)d_in[18];
    const float* ln1_b = (const float*)d_in[19];
    const float* ln2_g = (const float*)d_in[20];
    const float* ln2_b = (const float*)d_in[21];
    const float* wf = (const float*)d_in[22];
    const float* bf = (const float*)d_in[23];
    const float* bn_g = (const float*)d_in[24];
    const float* bn_b = (const float*)d_in[25];
    const float* bn_mean = (const float*)d_in[26];
    const float* bn_var = (const float*)d_in[27];

    char* ws = (char*)d_ws;
    size_t off = 0;
    auto alloc = [&](size_t bytes) { char* p = ws + off; off += (bytes + 255) & ~(size_t)255; return p; };

    u16* modalT[2]; u16* wbf[9]; u16* qT[2]; u16* kT[2]; u16* vC[2];
    u16* oatT[2]; float* mpreT[2]; u16* mlnT[2];
    for (int i = 0; i < 2; ++i) modalT[i] = (u16*)alloc(2LL * HW_N * 256 * 2);
    for (int i = 0; i < 9; ++i) wbf[i] = (u16*)alloc(131072 * 2);
    for (int i = 0; i < 2; ++i) qT[i] = (u16*)alloc(2LL * 512 * HW_N * 2);
    for (int i = 0; i < 2; ++i) kT[i] = (u16*)alloc(2LL * 512 * HW_N * 2);
    for (int i = 0; i < 2; ++i) vC[i] = (u16*)alloc(2LL * 512 * HW_N * 2);
    for (int i = 0; i < 2; ++i) oatT[i] = (u16*)alloc(2LL * 512 * HW_N * 2);
    for (int i = 0; i < 2; ++i) mpreT[i] = (float*)alloc(2LL * HW_N * 256 * 4);
    for (int i = 0; i < 2; ++i) mlnT[i] = (u16*)alloc(2LL * HW_N * 256 * 2);

    WPtrs wp;
    for (int j = 0; j < 6; ++j) { wp.s[j] = wqkv[j]; wp.d[j] = wbf[j]; }
    wp.s[6] = wo1; wp.d[6] = wbf[6];
    wp.s[7] = wo2; wp.d[7] = wbf[7];
    wp.s[8] = wf;  wp.d[8] = wbf[8];
    conv_w_kernel<<<dim3(128, 1, 9), 256, 0, stream>>>(wp);
    prep_modal_kernel<<<dim3(36, 4, 4), 256, 0, stream>>>(modal1, modal2, modalT[0], modalT[1]);

    GArgs g0 = {};
    for (int j = 0; j < 6; ++j) { g0.W[j] = wbf[j]; g0.bias[j] = bqkv[j]; }
    g0.X[0] = modalT[0]; g0.X[1] = modalT[1];
    for (int i = 0; i < 2; ++i) { g0.outQ[i] = qT[i]; g0.outK[i] = kT[i]; g0.outV[i] = vC[i]; }
    gemm_mfma<0><<<dim3(72, 2, 6), 256, 0, stream>>>(g0);

    attn_mfma_kernel<<<dim3(36 * 8 * 4), 256, 0, stream>>>(
        qT[0], kT[0], vC[0], qT[1], kT[1], vC[1], oatT[0], oatT[1]);

    GArgs g1a = {};
    g1a.W[0] = wbf[6]; g1a.W[1] = wbf[7];
    g1a.bias[0] = bo1; g1a.bias[1] = bo2;
    g1a.X[0] = oatT[0]; g1a.X[1] = oatT[1];
    g1a.R[0] = modalT[0]; g1a.R[1] = modalT[1];
    g1a.outT[0] = mpreT[0]; g1a.outT[1] = mpreT[1];
    gemm_mfma<1><<<dim3(36, 2, 2), 256, 0, stream>>>(g1a);

    ln_t_kernel<<<dim3(36, 2, 2), 256, 0, stream>>>(
        mpreT[0], mpreT[1], ln1_g, ln1_b, ln2_g, ln2_b, mlnT[0], mlnT[1]);

    GArgs g2a = {};
    g2a.W[0] = wbf[8]; g2a.bias[0] = bf;
    g2a.X[0] = mlnT[0]; g2a.X[1] = mlnT[1];
    g2a.outC = (float*)d_out;
    g2a.bnm = bn_mean; g2a.bnv = bn_var; g2a.bng = bn_g; g2a.bnb = bn_b;
    gemm_mfma<2><<<dim3(36, 2, 1), 256, 0, stream>>>(g2a);
}